// Round 1
// baseline (3753.941 us; speedup 1.0000x reference)
//
#include <hip/hip_runtime.h>
#include <math.h>

#define NN 25000
#define NE 100000
#define H 64

// ---------------- node MLP: h0 = L3(relu(L2(relu(L1 x)))) ----------------
__global__ __launch_bounds__(256) void node_mlp(
    const float* __restrict__ x,
    const float* __restrict__ Wn1, const float* __restrict__ bn1,
    const float* __restrict__ Wn2, const float* __restrict__ bn2,
    const float* __restrict__ Wn3, const float* __restrict__ bn3,
    float* __restrict__ h0)
{
    __shared__ float sx[4][32];
    __shared__ float sh1[4][64];
    int w = threadIdx.x >> 6, lane = threadIdx.x & 63;
    int n = blockIdx.x * 4 + w;
    if (n >= NN) return;                      // no barriers in this kernel
    if (lane < 32) sx[w][lane] = x[(size_t)n * 32 + lane];
    float a = bn1[lane];
    #pragma unroll
    for (int i = 0; i < 32; ++i) a += sx[w][i] * Wn1[lane * 32 + i];
    a = fmaxf(a, 0.f);
    sh1[w][lane] = a;
    float b = bn2[lane];
    #pragma unroll
    for (int i = 0; i < 64; ++i) b += sh1[w][i] * Wn2[lane * 64 + i];
    b = fmaxf(b, 0.f);
    sh1[w][lane] = b;                          // in-wave program order: safe
    float c = bn3[lane];
    #pragma unroll
    for (int i = 0; i < 64; ++i) c += sh1[w][i] * Wn3[lane * 64 + i];
    h0[(size_t)n * 64 + lane] = c;             // no relu on last layer
}

// ---------------- edge MLP (first two layers): ew2 = relu(L2(relu(L1 ea))) ----------------
__global__ __launch_bounds__(256) void edge_mlp(
    const float* __restrict__ ea,
    const float* __restrict__ We1, const float* __restrict__ be1,
    const float* __restrict__ We2, const float* __restrict__ be2,
    float* __restrict__ ew2)
{
    __shared__ float sa[4][16];
    __shared__ float st[4][64];
    int w = threadIdx.x >> 6, lane = threadIdx.x & 63;
    int e = blockIdx.x * 4 + w;
    if (e >= NE) return;
    if (lane < 16) sa[w][lane] = ea[(size_t)e * 16 + lane];
    float a = be1[lane];
    #pragma unroll
    for (int i = 0; i < 16; ++i) a += sa[w][i] * We1[lane * 16 + i];
    a = fmaxf(a, 0.f);
    st[w][lane] = a;
    float b = be2[lane];
    #pragma unroll
    for (int i = 0; i < 64; ++i) b += st[w][i] * We2[lane * 64 + i];
    ew2[(size_t)e * 64 + lane] = fmaxf(b, 0.f);
}

// ---------------- Wf prep: Wf[i*4096 + k*64 + o] = We3[(i*64+o)*64 + k] ----------------
__global__ __launch_bounds__(256) void wf_prep(const float* __restrict__ We3,
                                               float* __restrict__ Wf)
{
    int f = blockIdx.x * 256 + threadIdx.x;    // 0 .. 262143
    int o = f & 63, k = (f >> 6) & 63, i = f >> 12;
    Wf[f] = We3[(size_t)((i << 6) + o) * 64 + k];
}

// ---------------- message GEMM + scatter ----------------
// msg[E,64] = P[E,4096] @ Wf[4096,64], P[e, i*64+k] = h[src_e,i]*ew2[e,k],
// plus bias pass  msg[e,o] += sum_i h[src_e,i]*be3[i*64+o].
// 64 edges per block, 256 threads; thread = 4 edges x 4 outputs.
__global__ __launch_bounds__(256) void msg_kernel(
    const float* __restrict__ hsrc, const float* __restrict__ ew2,
    const float* __restrict__ Wf, const float* __restrict__ be3,
    const int* __restrict__ edge_index, float* __restrict__ aggr)
{
    __shared__ float sh_h[64][64];   // [i][e]  (transposed h_src rows)
    __shared__ float sh_e2[64][64];  // [k][e]  (transposed ew2 rows)
    __shared__ float sh_w[64][64];   // [k][o]  current i-slab of Wf (or be3)
    int t = threadIdx.x;
    int e0 = blockIdx.x * 64;

    // gather staging: 4 threads per edge, 16 floats each
    {
        int eg = t >> 2, part = t & 3;
        int e = e0 + eg;
        int ec = (e < NE) ? e : (NE - 1);
        int src = edge_index[ec];
        const float4* hrow = (const float4*)(hsrc + (size_t)src * 64);
        const float4* erow = (const float4*)(ew2 + (size_t)ec * 64);
        bool valid = (e < NE);
        #pragma unroll
        for (int j = 0; j < 4; ++j) {
            float4 hv = hrow[part * 4 + j];
            float4 ev = valid ? erow[part * 4 + j] : make_float4(0.f, 0.f, 0.f, 0.f);
            int c = part * 16 + j * 4;
            sh_h[c + 0][eg] = hv.x; sh_h[c + 1][eg] = hv.y;
            sh_h[c + 2][eg] = hv.z; sh_h[c + 3][eg] = hv.w;
            sh_e2[c + 0][eg] = ev.x; sh_e2[c + 1][eg] = ev.y;
            sh_e2[c + 2][eg] = ev.z; sh_e2[c + 3][eg] = ev.w;
        }
    }

    float acc[4][4];
    #pragma unroll
    for (int a = 0; a < 4; ++a)
        #pragma unroll
        for (int b = 0; b < 4; ++b) acc[a][b] = 0.f;

    const int to = t & 15, te = t >> 4;
    const int o0 = to * 4, te4 = te * 4;

    for (int i = 0; i < 64; ++i) {
        __syncthreads();
        {   // stage Wf slab for this i (16 KB, coalesced)
            const float4* s4 = (const float4*)(Wf + ((size_t)i << 12));
            float4* d4 = (float4*)&sh_w[0][0];
            #pragma unroll
            for (int j = 0; j < 4; ++j) d4[t + 256 * j] = s4[t + 256 * j];
        }
        __syncthreads();
        const float4 hv = *(const float4*)&sh_h[i][te4];
        float ph[4] = {hv.x, hv.y, hv.z, hv.w};
        #pragma unroll 8
        for (int k = 0; k < 64; ++k) {
            float4 ev = *(const float4*)&sh_e2[k][te4];
            float4 wv = *(const float4*)&sh_w[k][o0];
            float pv[4] = {ph[0] * ev.x, ph[1] * ev.y, ph[2] * ev.z, ph[3] * ev.w};
            float wa[4] = {wv.x, wv.y, wv.z, wv.w};
            #pragma unroll
            for (int ee = 0; ee < 4; ++ee)
                #pragma unroll
                for (int oo = 0; oo < 4; ++oo) acc[ee][oo] += pv[ee] * wa[oo];
        }
    }

    // bias pass: P[e,k] = h[e,k], W = be3
    __syncthreads();
    {
        const float4* s4 = (const float4*)be3;
        float4* d4 = (float4*)&sh_w[0][0];
        #pragma unroll
        for (int j = 0; j < 4; ++j) d4[t + 256 * j] = s4[t + 256 * j];
    }
    __syncthreads();
    #pragma unroll 8
    for (int k = 0; k < 64; ++k) {
        float4 pvv = *(const float4*)&sh_h[k][te4];
        float4 wv  = *(const float4*)&sh_w[k][o0];
        float pv[4] = {pvv.x, pvv.y, pvv.z, pvv.w};
        float wa[4] = {wv.x, wv.y, wv.z, wv.w};
        #pragma unroll
        for (int ee = 0; ee < 4; ++ee)
            #pragma unroll
            for (int oo = 0; oo < 4; ++oo) acc[ee][oo] += pv[ee] * wa[oo];
    }

    // scatter-add to aggr[dst]
    #pragma unroll
    for (int ee = 0; ee < 4; ++ee) {
        int e = e0 + te4 + ee;
        if (e >= NE) continue;
        int d = edge_index[NE + e];
        float* ap = aggr + (size_t)d * 64 + o0;
        atomicAdd(ap + 0, acc[ee][0]);
        atomicAdd(ap + 1, acc[ee][1]);
        atomicAdd(ap + 2, acc[ee][2]);
        atomicAdd(ap + 3, acc[ee][3]);
    }
}

// ---------------- fused root-term + GRU step ----------------
__global__ __launch_bounds__(256) void gru_kernel(
    const float* __restrict__ aggr, float* __restrict__ hbuf, float* __restrict__ hid,
    const float* __restrict__ root, const float* __restrict__ cbias,
    const float* __restrict__ Wih, const float* __restrict__ Whh,
    const float* __restrict__ bih, const float* __restrict__ bhh,
    float* __restrict__ out2)
{
    __shared__ float sm[4][2][64];
    int w = threadIdx.x >> 6, lane = threadIdx.x & 63;
    int n = blockIdx.x * 4 + w;
    if (n >= NN) return;                       // no barriers
    size_t idx = (size_t)n * 64 + lane;
    float hv   = hbuf[idx];
    float hidv = hid[idx];
    sm[w][0][lane] = hv;
    sm[w][1][lane] = hidv;
    float m = aggr[idx] + cbias[lane];
    #pragma unroll
    for (int i = 0; i < 64; ++i) m += sm[w][0][i] * root[i * 64 + lane];
    sm[w][0][lane] = m;                        // in-wave program order: safe
    float gr = bih[lane], gz = bih[64 + lane], gn = bih[128 + lane];
    #pragma unroll
    for (int i = 0; i < 64; ++i) {
        float mi = sm[w][0][i];
        gr += mi * Wih[lane * 64 + i];
        gz += mi * Wih[(64 + lane) * 64 + i];
        gn += mi * Wih[(128 + lane) * 64 + i];
    }
    float hr = bhh[lane], hz = bhh[64 + lane], hn = bhh[128 + lane];
    #pragma unroll
    for (int i = 0; i < 64; ++i) {
        float hi2 = sm[w][1][i];
        hr += hi2 * Whh[lane * 64 + i];
        hz += hi2 * Whh[(64 + lane) * 64 + i];
        hn += hi2 * Whh[(128 + lane) * 64 + i];
    }
    float r  = 1.f / (1.f + expf(-(gr + hr)));
    float z  = 1.f / (1.f + expf(-(gz + hz)));
    float nn = tanhf(gn + r * hn);
    float outv = (1.f - z) * nn + z * hidv;
    hbuf[idx] = outv;
    hid[idx]  = outv;
    if (out2) out2[idx] = outv;
}

extern "C" void kernel_launch(void* const* d_in, const int* in_sizes, int n_in,
                              void* d_out, int out_size, void* d_ws, size_t ws_size,
                              hipStream_t stream)
{
    const float* x   = (const float*)d_in[0];
    const float* ea  = (const float*)d_in[1];
    const float* Wn1 = (const float*)d_in[2];  const float* bn1 = (const float*)d_in[3];
    const float* Wn2 = (const float*)d_in[4];  const float* bn2 = (const float*)d_in[5];
    const float* Wn3 = (const float*)d_in[6];  const float* bn3 = (const float*)d_in[7];
    const float* We1 = (const float*)d_in[8];  const float* be1 = (const float*)d_in[9];
    const float* We2 = (const float*)d_in[10]; const float* be2 = (const float*)d_in[11];
    const float* We3 = (const float*)d_in[12]; const float* be3 = (const float*)d_in[13];
    const float* roots = (const float*)d_in[14];
    const float* cb    = (const float*)d_in[15];
    const float* Wih = (const float*)d_in[16]; const float* Whh = (const float*)d_in[17];
    const float* bih = (const float*)d_in[18]; const float* bhh = (const float*)d_in[19];
    const int*   ei  = (const int*)d_in[20];

    // workspace layout (fp32), ~45.9 MB total
    float* ws   = (float*)d_ws;
    float* hbuf = ws;                               // N*64
    float* hid  = hbuf + (size_t)NN * 64;           // N*64
    float* ew2  = hid  + (size_t)NN * 64;           // E*64
    float* Wf   = ew2  + (size_t)NE * 64;           // 4096*64
    float* aggr = Wf   + 4096 * 64;                 // N*64

    node_mlp<<<(NN + 3) / 4, 256, 0, stream>>>(x, Wn1, bn1, Wn2, bn2, Wn3, bn3, hbuf);
    edge_mlp<<<(NE + 3) / 4, 256, 0, stream>>>(ea, We1, be1, We2, be2, ew2);
    wf_prep<<<(4096 * 64) / 256, 256, 0, stream>>>(We3, Wf);
    hipMemsetAsync(hid, 0, (size_t)NN * 64 * sizeof(float), stream);

    for (int l = 0; l < 3; ++l) {
        hipMemsetAsync(aggr, 0, (size_t)NN * 64 * sizeof(float), stream);
        msg_kernel<<<(NE + 63) / 64, 256, 0, stream>>>(hbuf, ew2, Wf, be3, ei, aggr);
        gru_kernel<<<(NN + 3) / 4, 256, 0, stream>>>(aggr, hbuf, hid,
            roots + (size_t)l * 4096, cb + (size_t)l * 64,
            Wih, Whh, bih, bhh, (l == 2) ? (float*)d_out : nullptr);
    }
}

// Round 3
// 1787.241 us; speedup vs baseline: 2.1004x; 2.1004x over previous
//
#include <hip/hip_runtime.h>
#include <math.h>

#define NN 25000
#define NE 100000

typedef _Float16 f16;
typedef _Float16 half8 __attribute__((ext_vector_type(8)));
typedef float f32x4 __attribute__((ext_vector_type(4)));

// ---------------- one-time weight prep ----------------
// Wf16: 65 K-slabs of [64 o][64 k] fp16. Slabs 0..63 are We3 rows verbatim
// (We3[(i*64+o)][k] is already [i][o][k] order); slab 64 is be3 transposed.
__global__ __launch_bounds__(256) void wf_prep(const float* __restrict__ We3,
                                               const float* __restrict__ be3,
                                               f16* __restrict__ Wf16)
{
    int f = blockIdx.x * 256 + threadIdx.x;          // 0 .. 266239
    if (f >= 266240) return;
    if (f < 262144) Wf16[f] = (f16)We3[f];
    else {
        int j = f - 262144; int o = (j >> 6), k = j & 63;
        Wf16[f] = (f16)be3[k * 64 + o];
    }
}

// transposed fp32 weights so per-lane reads are coalesced (lane = out index)
__global__ __launch_bounds__(256) void prep_t(
    const float* __restrict__ Wn1, const float* __restrict__ Wn2,
    const float* __restrict__ Wn3, const float* __restrict__ We1,
    const float* __restrict__ We2, const float* __restrict__ Wih,
    const float* __restrict__ Whh, float* __restrict__ T)
{
    int f = blockIdx.x * 256 + threadIdx.x;
    if (f >= 39936) return;
    if (f < 2048)       { int j = f;         T[f] = Wn1[(j & 63) * 32 + (j >> 6)]; }
    else if (f < 6144)  { int j = f - 2048;  T[f] = Wn2[(j & 63) * 64 + (j >> 6)]; }
    else if (f < 10240) { int j = f - 6144;  T[f] = Wn3[(j & 63) * 64 + (j >> 6)]; }
    else if (f < 11264) { int j = f - 10240; T[f] = We1[(j & 63) * 16 + (j >> 6)]; }
    else if (f < 15360) { int j = f - 11264; T[f] = We2[(j & 63) * 64 + (j >> 6)]; }
    else if (f < 27648) { int j = f - 15360; T[f] = Wih[(j % 192) * 64 + (j / 192)]; }
    else                { int j = f - 27648; T[f] = Whh[(j % 192) * 64 + (j / 192)]; }
}

// ---------------- node MLP ----------------
__global__ __launch_bounds__(256) void node_mlp(
    const float* __restrict__ x, const float* __restrict__ T,
    const float* __restrict__ bn1, const float* __restrict__ bn2,
    const float* __restrict__ bn3,
    float* __restrict__ h0, f16* __restrict__ h16)
{
    __shared__ float sx[4][32];
    __shared__ float sh1[4][64];
    const float* Wn1T = T;            // [32][64]
    const float* Wn2T = T + 2048;     // [64][64]
    const float* Wn3T = T + 6144;     // [64][64]
    int w = threadIdx.x >> 6, lane = threadIdx.x & 63;
    int n = blockIdx.x * 4 + w;
    if (n >= NN) return;                      // wave-private LDS slice, no barriers
    if (lane < 32) sx[w][lane] = x[(size_t)n * 32 + lane];
    float a = bn1[lane];
    #pragma unroll
    for (int i = 0; i < 32; ++i) a += sx[w][i] * Wn1T[i * 64 + lane];
    a = fmaxf(a, 0.f);
    sh1[w][lane] = a;
    float b = bn2[lane];
    #pragma unroll
    for (int i = 0; i < 64; ++i) b += sh1[w][i] * Wn2T[i * 64 + lane];
    b = fmaxf(b, 0.f);
    sh1[w][lane] = b;
    float c = bn3[lane];
    #pragma unroll
    for (int i = 0; i < 64; ++i) c += sh1[w][i] * Wn3T[i * 64 + lane];
    size_t idx = (size_t)n * 64 + lane;
    h0[idx] = c;
    h16[idx] = (f16)c;
}

// ---------------- edge MLP (2 layers) -> fp16 ----------------
__global__ __launch_bounds__(256) void edge_mlp(
    const float* __restrict__ ea, const float* __restrict__ T,
    const float* __restrict__ be1, const float* __restrict__ be2,
    f16* __restrict__ ew16)
{
    __shared__ float sa[4][16];
    __shared__ float st[4][64];
    const float* We1T = T + 10240;    // [16][64]
    const float* We2T = T + 11264;    // [64][64]
    int w = threadIdx.x >> 6, lane = threadIdx.x & 63;
    int e = blockIdx.x * 4 + w;
    if (e >= NE) return;
    if (lane < 16) sa[w][lane] = ea[(size_t)e * 16 + lane];
    float a = be1[lane];
    #pragma unroll
    for (int i = 0; i < 16; ++i) a += sa[w][i] * We1T[i * 64 + lane];
    a = fmaxf(a, 0.f);
    st[w][lane] = a;
    float b = be2[lane];
    #pragma unroll
    for (int i = 0; i < 64; ++i) b += st[w][i] * We2T[i * 64 + lane];
    ew16[(size_t)e * 64 + lane] = (f16)fmaxf(b, 0.f);
}

// ---------------- message GEMM (MFMA f16) + scatter ----------------
// msg[E,64] = P[E,4160] @ [Wf16; be3T], P[e, i*64+k] = h16[src_e,i]*ew16[e,k]
// (last 64-slab: P = h16 directly, B = be3T -> folds the be3 bias term).
// Block: 64 edges x 64 outputs, 4 waves; wave = 16 edges x 64 outs.
// A from LDS (rows padded to 72 f16 = 144B: bank-minimum b128 reads);
// B straight from global Wf16 (532 KB, L1/L2-resident, same for all waves)
// -> zero barriers in the K-loop.
__global__ __launch_bounds__(256) void msg_mfma(
    const f16* __restrict__ h16, const f16* __restrict__ ew16,
    const f16* __restrict__ Wf16, const int* __restrict__ edge_index,
    float* __restrict__ aggr)
{
    __shared__ f16 sh_h[64][72];
    __shared__ f16 sh_e[64][72];
    __shared__ int sh_dst[64];
    int t = threadIdx.x;
    int e0 = blockIdx.x * 64;

    {   // gather-stage 64 h-rows + 64 ew-rows as fp16; 4 threads/row
        int row = t >> 2, part = t & 3;
        int e = e0 + row;
        bool valid = e < NE;
        int ec = valid ? e : NE - 1;
        int src = edge_index[ec];
        const f16* hp = h16 + (size_t)src * 64 + part * 16;
        const f16* ep = ew16 + (size_t)ec * 64 + part * 16;
        uint4 z = make_uint4(0u, 0u, 0u, 0u);
        uint4 h0 = valid ? *(const uint4*)hp : z;
        uint4 h1 = valid ? *(const uint4*)(hp + 8) : z;
        uint4 e0v = valid ? *(const uint4*)ep : z;
        uint4 e1v = valid ? *(const uint4*)(ep + 8) : z;
        *(uint4*)&sh_h[row][part * 16]     = h0;
        *(uint4*)&sh_h[row][part * 16 + 8] = h1;
        *(uint4*)&sh_e[row][part * 16]     = e0v;
        *(uint4*)&sh_e[row][part * 16 + 8] = e1v;
        if (t < 64) sh_dst[t] = (e0 + t < NE) ? edge_index[NE + e0 + t] : -1;
    }
    __syncthreads();

    int lane = t & 63, wv = t >> 6;
    int r16 = lane & 15, kq = lane >> 4;            // A row / C col ; k-quarter
    int row = wv * 16 + r16;
    f32x4 acc0 = {0,0,0,0}, acc1 = {0,0,0,0}, acc2 = {0,0,0,0}, acc3 = {0,0,0,0};
    const f16* wp = Wf16 + (size_t)(r16 * 64 + kq * 8);  // lane base into B slabs

    for (int i = 0; i < 64; ++i) {                  // main K: rank-1 A slabs
        f16 hs = sh_h[row][i];
        half8 hv = { hs, hs, hs, hs, hs, hs, hs, hs };
        half8 a0 = (*(const half8*)&sh_e[row][kq * 8]) * hv;        // k 0..31
        half8 a1 = (*(const half8*)&sh_e[row][32 + kq * 8]) * hv;   // k 32..63
        const f16* wi = wp + (size_t)i * 4096;
        #pragma unroll
        for (int nt = 0; nt < 4; ++nt) {
            half8 b0 = *(const half8*)(wi + nt * 1024);
            half8 b1 = *(const half8*)(wi + nt * 1024 + 32);
            f32x4* ac = nt == 0 ? &acc0 : nt == 1 ? &acc1 : nt == 2 ? &acc2 : &acc3;
            *ac = __builtin_amdgcn_mfma_f32_16x16x32_f16(a0, b0, *ac, 0, 0, 0);
            *ac = __builtin_amdgcn_mfma_f32_16x16x32_f16(a1, b1, *ac, 0, 0, 0);
        }
    }
    {   // bias slab: A = h16 rows, B = be3T
        half8 a0 = *(const half8*)&sh_h[row][kq * 8];
        half8 a1 = *(const half8*)&sh_h[row][32 + kq * 8];
        const f16* wi = wp + (size_t)64 * 4096;
        #pragma unroll
        for (int nt = 0; nt < 4; ++nt) {
            half8 b0 = *(const half8*)(wi + nt * 1024);
            half8 b1 = *(const half8*)(wi + nt * 1024 + 32);
            f32x4* ac = nt == 0 ? &acc0 : nt == 1 ? &acc1 : nt == 2 ? &acc2 : &acc3;
            *ac = __builtin_amdgcn_mfma_f32_16x16x32_f16(a0, b0, *ac, 0, 0, 0);
            *ac = __builtin_amdgcn_mfma_f32_16x16x32_f16(a1, b1, *ac, 0, 0, 0);
        }
    }

    // scatter: C/D layout col=lane&15, row=(lane>>4)*4+reg  [m89-verified]
    #pragma unroll
    for (int reg = 0; reg < 4; ++reg) {
        int e_l = wv * 16 + kq * 4 + reg;
        int d = sh_dst[e_l];
        if (d >= 0) {
            float* ap = aggr + (size_t)d * 64 + r16;
            atomicAdd(ap,      acc0[reg]);
            atomicAdd(ap + 16, acc1[reg]);
            atomicAdd(ap + 32, acc2[reg]);
            atomicAdd(ap + 48, acc3[reg]);
        }
    }
}

// ---------------- fused root-term + GRU step ----------------
__global__ __launch_bounds__(256) void gru_kernel(
    const float* __restrict__ aggr, float* __restrict__ hbuf, float* __restrict__ hid,
    f16* __restrict__ h16,
    const float* __restrict__ root, const float* __restrict__ cbias,
    const float* __restrict__ T,
    const float* __restrict__ bih, const float* __restrict__ bhh,
    float* __restrict__ out2)
{
    __shared__ float sm[4][2][64];
    const float* WihT = T + 15360;    // [64][192]
    const float* WhhT = T + 27648;    // [64][192]
    int w = threadIdx.x >> 6, lane = threadIdx.x & 63;
    int n = blockIdx.x * 4 + w;
    if (n >= NN) return;
    size_t idx = (size_t)n * 64 + lane;
    float hv   = hbuf[idx];
    float hidv = hid[idx];
    sm[w][0][lane] = hv;
    sm[w][1][lane] = hidv;
    float m = aggr[idx] + cbias[lane];
    #pragma unroll
    for (int i = 0; i < 64; ++i) m += sm[w][0][i] * root[i * 64 + lane];
    sm[w][0][lane] = m;                        // in-wave program order: safe
    float gr = bih[lane], gz = bih[64 + lane], gn = bih[128 + lane];
    #pragma unroll
    for (int i = 0; i < 64; ++i) {
        float mi = sm[w][0][i];
        gr += mi * WihT[i * 192 + lane];
        gz += mi * WihT[i * 192 + 64 + lane];
        gn += mi * WihT[i * 192 + 128 + lane];
    }
    float hr = bhh[lane], hz = bhh[64 + lane], hn = bhh[128 + lane];
    #pragma unroll
    for (int i = 0; i < 64; ++i) {
        float hi2 = sm[w][1][i];
        hr += hi2 * WhhT[i * 192 + lane];
        hz += hi2 * WhhT[i * 192 + 64 + lane];
        hn += hi2 * WhhT[i * 192 + 128 + lane];
    }
    float r  = 1.f / (1.f + expf(-(gr + hr)));
    float z  = 1.f / (1.f + expf(-(gz + hz)));
    float nn = tanhf(gn + r * hn);
    float outv = (1.f - z) * nn + z * hidv;
    hbuf[idx] = outv;
    hid[idx]  = outv;
    h16[idx]  = (f16)outv;
    if (out2) out2[idx] = outv;
}

extern "C" void kernel_launch(void* const* d_in, const int* in_sizes, int n_in,
                              void* d_out, int out_size, void* d_ws, size_t ws_size,
                              hipStream_t stream)
{
    const float* x   = (const float*)d_in[0];
    const float* ea  = (const float*)d_in[1];
    const float* Wn1 = (const float*)d_in[2];  const float* bn1 = (const float*)d_in[3];
    const float* Wn2 = (const float*)d_in[4];  const float* bn2 = (const float*)d_in[5];
    const float* Wn3 = (const float*)d_in[6];  const float* bn3 = (const float*)d_in[7];
    const float* We1 = (const float*)d_in[8];  const float* be1 = (const float*)d_in[9];
    const float* We2 = (const float*)d_in[10]; const float* be2 = (const float*)d_in[11];
    const float* We3 = (const float*)d_in[12]; const float* be3 = (const float*)d_in[13];
    const float* roots = (const float*)d_in[14];
    const float* cb    = (const float*)d_in[15];
    const float* Wih = (const float*)d_in[16]; const float* Whh = (const float*)d_in[17];
    const float* bih = (const float*)d_in[18]; const float* bhh = (const float*)d_in[19];
    const int*   ei  = (const int*)d_in[20];

    // ws layout: fp32 region then fp16 region (16B-aligned), ~35.9 MB total
    float* ws   = (float*)d_ws;
    float* hbuf = ws;                               // N*64
    float* hid  = hbuf + (size_t)NN * 64;           // N*64
    float* aggr = hid  + (size_t)NN * 64;           // N*64
    float* Tbuf = aggr + (size_t)NN * 64;           // 39936 (pad to 40960)
    f16*   h16  = (f16*)(ws + 3 * (size_t)NN * 64 + 40960);   // N*64
    f16*   ew16 = h16  + (size_t)NN * 64;                     // E*64
    f16*   Wf16 = ew16 + (size_t)NE * 64;                     // 65*4096

    prep_t <<<(39936 + 255) / 256, 256, 0, stream>>>(Wn1, Wn2, Wn3, We1, We2, Wih, Whh, Tbuf);
    wf_prep<<<(266240 + 255) / 256, 256, 0, stream>>>(We3, be3, Wf16);
    node_mlp<<<(NN + 3) / 4, 256, 0, stream>>>(x, Tbuf, bn1, bn2, bn3, hbuf, h16);
    edge_mlp<<<(NE + 3) / 4, 256, 0, stream>>>(ea, Tbuf, be1, be2, ew16);
    hipMemsetAsync(hid, 0, (size_t)NN * 64 * sizeof(float), stream);

    for (int l = 0; l < 3; ++l) {
        hipMemsetAsync(aggr, 0, (size_t)NN * 64 * sizeof(float), stream);
        msg_mfma<<<(NE + 63) / 64, 256, 0, stream>>>(h16, ew16, Wf16, ei, aggr);
        gru_kernel<<<(NN + 3) / 4, 256, 0, stream>>>(aggr, hbuf, hid, h16,
            roots + (size_t)l * 4096, cb + (size_t)l * 64,
            Tbuf, bih, bhh, (l == 2) ? (float*)d_out : nullptr);
    }
}

// Round 4
// 1066.562 us; speedup vs baseline: 3.5197x; 1.6757x over previous
//
#include <hip/hip_runtime.h>
#include <math.h>

#define NN 25000
#define NE 100000

typedef _Float16 f16;
typedef _Float16 half8 __attribute__((ext_vector_type(8)));
typedef float f32x4 __attribute__((ext_vector_type(4)));

// ---------------- one-time weight prep ----------------
// Wf16: 65 K-slabs of [64 o][64 k] fp16. Slabs 0..63 are We3 rows verbatim
// (We3[(i*64+o)][k] is already [i][o][k] order); slab 64 is be3 transposed.
__global__ __launch_bounds__(256) void wf_prep(const float* __restrict__ We3,
                                               const float* __restrict__ be3,
                                               f16* __restrict__ Wf16)
{
    int f = blockIdx.x * 256 + threadIdx.x;          // 0 .. 266239
    if (f >= 266240) return;
    if (f < 262144) Wf16[f] = (f16)We3[f];
    else {
        int j = f - 262144; int o = (j >> 6), k = j & 63;
        Wf16[f] = (f16)be3[k * 64 + o];
    }
}

// transposed fp32 weights so per-lane reads are coalesced (lane = out index)
__global__ __launch_bounds__(256) void prep_t(
    const float* __restrict__ Wn1, const float* __restrict__ Wn2,
    const float* __restrict__ Wn3, const float* __restrict__ We1,
    const float* __restrict__ We2, const float* __restrict__ Wih,
    const float* __restrict__ Whh, float* __restrict__ T)
{
    int f = blockIdx.x * 256 + threadIdx.x;
    if (f >= 39936) return;
    if (f < 2048)       { int j = f;         T[f] = Wn1[(j & 63) * 32 + (j >> 6)]; }
    else if (f < 6144)  { int j = f - 2048;  T[f] = Wn2[(j & 63) * 64 + (j >> 6)]; }
    else if (f < 10240) { int j = f - 6144;  T[f] = Wn3[(j & 63) * 64 + (j >> 6)]; }
    else if (f < 11264) { int j = f - 10240; T[f] = We1[(j & 63) * 16 + (j >> 6)]; }
    else if (f < 15360) { int j = f - 11264; T[f] = We2[(j & 63) * 64 + (j >> 6)]; }
    else if (f < 27648) { int j = f - 15360; T[f] = Wih[(j % 192) * 64 + (j / 192)]; }
    else                { int j = f - 27648; T[f] = Whh[(j % 192) * 64 + (j / 192)]; }
}

// ---------------- node MLP ----------------
__global__ __launch_bounds__(256) void node_mlp(
    const float* __restrict__ x, const float* __restrict__ T,
    const float* __restrict__ bn1, const float* __restrict__ bn2,
    const float* __restrict__ bn3,
    float* __restrict__ h0, f16* __restrict__ h16)
{
    __shared__ float sx[4][32];
    __shared__ float sh1[4][64];
    const float* Wn1T = T;            // [32][64]
    const float* Wn2T = T + 2048;     // [64][64]
    const float* Wn3T = T + 6144;     // [64][64]
    int w = threadIdx.x >> 6, lane = threadIdx.x & 63;
    int n = blockIdx.x * 4 + w;
    if (n >= NN) return;                      // wave-private LDS slice, no barriers
    if (lane < 32) sx[w][lane] = x[(size_t)n * 32 + lane];
    float a = bn1[lane];
    #pragma unroll
    for (int i = 0; i < 32; ++i) a += sx[w][i] * Wn1T[i * 64 + lane];
    a = fmaxf(a, 0.f);
    sh1[w][lane] = a;
    float b = bn2[lane];
    #pragma unroll
    for (int i = 0; i < 64; ++i) b += sh1[w][i] * Wn2T[i * 64 + lane];
    b = fmaxf(b, 0.f);
    sh1[w][lane] = b;
    float c = bn3[lane];
    #pragma unroll
    for (int i = 0; i < 64; ++i) c += sh1[w][i] * Wn3T[i * 64 + lane];
    size_t idx = (size_t)n * 64 + lane;
    h0[idx] = c;
    h16[idx] = (f16)c;
}

// ---------------- edge MLP (2 layers) -> fp16 ----------------
__global__ __launch_bounds__(256) void edge_mlp(
    const float* __restrict__ ea, const float* __restrict__ T,
    const float* __restrict__ be1, const float* __restrict__ be2,
    f16* __restrict__ ew16)
{
    __shared__ float sa[4][16];
    __shared__ float st[4][64];
    const float* We1T = T + 10240;    // [16][64]
    const float* We2T = T + 11264;    // [64][64]
    int w = threadIdx.x >> 6, lane = threadIdx.x & 63;
    int e = blockIdx.x * 4 + w;
    if (e >= NE) return;
    if (lane < 16) sa[w][lane] = ea[(size_t)e * 16 + lane];
    float a = be1[lane];
    #pragma unroll
    for (int i = 0; i < 16; ++i) a += sa[w][i] * We1T[i * 64 + lane];
    a = fmaxf(a, 0.f);
    st[w][lane] = a;
    float b = be2[lane];
    #pragma unroll
    for (int i = 0; i < 64; ++i) b += st[w][i] * We2T[i * 64 + lane];
    ew16[(size_t)e * 64 + lane] = (f16)fmaxf(b, 0.f);
}

// ---------------- message GEMM (MFMA f16) + scatter ----------------
// msg[E,64] = P[E,4160] @ [Wf16; be3T], P[e, i*64+k] = h16[src_e,i]*ew16[e,k].
// Block: 128 edges x 64 outputs, 4 waves; wave = 32 edges (2 M-subtiles).
// A built on the fly from LDS (rows padded to 72 f16); B frags fetched from
// global (L1-resident, shared by all waves) with 1-slab REGISTER PREFETCH:
// slab i+1's 8 frags are issued before the A-build+MFMA of slab i, so the
// ~150cy L1 latency hides under ~220cy of VALU+MFMA. No barriers in K-loop.
__global__ __launch_bounds__(256) void msg_mfma(
    const f16* __restrict__ h16, const f16* __restrict__ ew16,
    const f16* __restrict__ Wf16, const int* __restrict__ edge_index,
    float* __restrict__ aggr)
{
    __shared__ f16 sh_h[128][72];
    __shared__ f16 sh_e[128][72];
    __shared__ int sh_dst[128];
    int t = threadIdx.x;
    int e0 = blockIdx.x * 128;

    {   // gather-stage 128 h-rows + 128 ew-rows as fp16; 2 threads/row
        int row = t >> 1, part = t & 1;
        int e = e0 + row;
        bool valid = e < NE;
        int ec = valid ? e : NE - 1;
        int src = edge_index[ec];
        const f16* hp = h16 + (size_t)src * 64 + part * 32;
        const f16* ep = ew16 + (size_t)ec * 64 + part * 32;
        uint4 z = make_uint4(0u, 0u, 0u, 0u);
        uint4 h0 = valid ? *(const uint4*)hp : z;
        uint4 h1 = valid ? *(const uint4*)(hp + 8) : z;
        uint4 h2 = valid ? *(const uint4*)(hp + 16) : z;
        uint4 h3 = valid ? *(const uint4*)(hp + 24) : z;
        uint4 g0 = valid ? *(const uint4*)ep : z;
        uint4 g1 = valid ? *(const uint4*)(ep + 8) : z;
        uint4 g2 = valid ? *(const uint4*)(ep + 16) : z;
        uint4 g3 = valid ? *(const uint4*)(ep + 24) : z;
        *(uint4*)&sh_h[row][part * 32]      = h0;
        *(uint4*)&sh_h[row][part * 32 + 8]  = h1;
        *(uint4*)&sh_h[row][part * 32 + 16] = h2;
        *(uint4*)&sh_h[row][part * 32 + 24] = h3;
        *(uint4*)&sh_e[row][part * 32]      = g0;
        *(uint4*)&sh_e[row][part * 32 + 8]  = g1;
        *(uint4*)&sh_e[row][part * 32 + 16] = g2;
        *(uint4*)&sh_e[row][part * 32 + 24] = g3;
        if (t < 128) sh_dst[t] = (e0 + t < NE) ? edge_index[NE + e0 + t] : -1;
    }
    __syncthreads();

    int lane = t & 63, wv = t >> 6;
    int r16 = lane & 15, kq = lane >> 4;            // A/C row-col ; k-quarter
    int row0 = wv * 32 + r16;                       // M-subtile 0 row
    int row1 = row0 + 16;                           // M-subtile 1 row
    f32x4 acc[2][4];
    #pragma unroll
    for (int m = 0; m < 2; ++m)
        #pragma unroll
        for (int n = 0; n < 4; ++n) acc[m][n] = (f32x4){0,0,0,0};

    const f16* wp = Wf16 + (size_t)(r16 * 64 + kq * 8);  // lane base into B slabs

    // prologue: load slab 0 frags
    half8 b0 = *(const half8*)(wp);
    half8 b1 = *(const half8*)(wp + 32);
    half8 b2 = *(const half8*)(wp + 1024);
    half8 b3 = *(const half8*)(wp + 1024 + 32);
    half8 b4 = *(const half8*)(wp + 2048);
    half8 b5 = *(const half8*)(wp + 2048 + 32);
    half8 b6 = *(const half8*)(wp + 3072);
    half8 b7 = *(const half8*)(wp + 3072 + 32);

    for (int i = 0; i < 64; ++i) {
        // prefetch slab i+1 (slab 64 = bias slab, always valid)
        const f16* wn = wp + (size_t)(i + 1) * 4096;
        half8 n0 = *(const half8*)(wn);
        half8 n1 = *(const half8*)(wn + 32);
        half8 n2 = *(const half8*)(wn + 1024);
        half8 n3 = *(const half8*)(wn + 1024 + 32);
        half8 n4 = *(const half8*)(wn + 2048);
        half8 n5 = *(const half8*)(wn + 2048 + 32);
        half8 n6 = *(const half8*)(wn + 3072);
        half8 n7 = *(const half8*)(wn + 3072 + 32);

        // A-build (VALU) + MFMAs on current slab's frags
        #pragma unroll
        for (int m = 0; m < 2; ++m) {
            int row = m == 0 ? row0 : row1;
            f16 hs = sh_h[row][i];
            half8 hv8 = { hs, hs, hs, hs, hs, hs, hs, hs };
            half8 a0 = (*(const half8*)&sh_e[row][kq * 8]) * hv8;       // k 0..31
            half8 a1 = (*(const half8*)&sh_e[row][32 + kq * 8]) * hv8;  // k 32..63
            acc[m][0] = __builtin_amdgcn_mfma_f32_16x16x32_f16(a0, b0, acc[m][0], 0, 0, 0);
            acc[m][0] = __builtin_amdgcn_mfma_f32_16x16x32_f16(a1, b1, acc[m][0], 0, 0, 0);
            acc[m][1] = __builtin_amdgcn_mfma_f32_16x16x32_f16(a0, b2, acc[m][1], 0, 0, 0);
            acc[m][1] = __builtin_amdgcn_mfma_f32_16x16x32_f16(a1, b3, acc[m][1], 0, 0, 0);
            acc[m][2] = __builtin_amdgcn_mfma_f32_16x16x32_f16(a0, b4, acc[m][2], 0, 0, 0);
            acc[m][2] = __builtin_amdgcn_mfma_f32_16x16x32_f16(a1, b5, acc[m][2], 0, 0, 0);
            acc[m][3] = __builtin_amdgcn_mfma_f32_16x16x32_f16(a0, b6, acc[m][3], 0, 0, 0);
            acc[m][3] = __builtin_amdgcn_mfma_f32_16x16x32_f16(a1, b7, acc[m][3], 0, 0, 0);
        }
        b0 = n0; b1 = n1; b2 = n2; b3 = n3;
        b4 = n4; b5 = n5; b6 = n6; b7 = n7;
    }

    {   // bias slab (i=64): A = h16 rows, B = be3T (already in b0..b7)
        #pragma unroll
        for (int m = 0; m < 2; ++m) {
            int row = m == 0 ? row0 : row1;
            half8 a0 = *(const half8*)&sh_h[row][kq * 8];
            half8 a1 = *(const half8*)&sh_h[row][32 + kq * 8];
            acc[m][0] = __builtin_amdgcn_mfma_f32_16x16x32_f16(a0, b0, acc[m][0], 0, 0, 0);
            acc[m][0] = __builtin_amdgcn_mfma_f32_16x16x32_f16(a1, b1, acc[m][0], 0, 0, 0);
            acc[m][1] = __builtin_amdgcn_mfma_f32_16x16x32_f16(a0, b2, acc[m][1], 0, 0, 0);
            acc[m][1] = __builtin_amdgcn_mfma_f32_16x16x32_f16(a1, b3, acc[m][1], 0, 0, 0);
            acc[m][2] = __builtin_amdgcn_mfma_f32_16x16x32_f16(a0, b4, acc[m][2], 0, 0, 0);
            acc[m][2] = __builtin_amdgcn_mfma_f32_16x16x32_f16(a1, b5, acc[m][2], 0, 0, 0);
            acc[m][3] = __builtin_amdgcn_mfma_f32_16x16x32_f16(a0, b6, acc[m][3], 0, 0, 0);
            acc[m][3] = __builtin_amdgcn_mfma_f32_16x16x32_f16(a1, b7, acc[m][3], 0, 0, 0);
        }
    }

    // scatter: C/D layout col=lane&15, row=(lane>>4)*4+reg  [m89-verified]
    #pragma unroll
    for (int m = 0; m < 2; ++m) {
        #pragma unroll
        for (int reg = 0; reg < 4; ++reg) {
            int e_l = wv * 32 + m * 16 + kq * 4 + reg;
            int d = sh_dst[e_l];
            if (d >= 0) {
                float* ap = aggr + (size_t)d * 64 + r16;
                atomicAdd(ap,      acc[m][0][reg]);
                atomicAdd(ap + 16, acc[m][1][reg]);
                atomicAdd(ap + 32, acc[m][2][reg]);
                atomicAdd(ap + 48, acc[m][3][reg]);
            }
        }
    }
}

// ---------------- fused root-term + GRU step: 4 nodes per wave ----------------
// Weight rows loaded once per wave serve 4 nodes (global traffic /4);
// cross-element broadcasts from LDS vectorized as float4. Math stays fp32.
__global__ __launch_bounds__(256) void gru_kernel(
    const float* __restrict__ aggr, float* __restrict__ hbuf, float* __restrict__ hid,
    f16* __restrict__ h16,
    const float* __restrict__ root, const float* __restrict__ cbias,
    const float* __restrict__ T,
    const float* __restrict__ bih, const float* __restrict__ bhh,
    float* __restrict__ out2)
{
    __shared__ float sm_h[4][4][64];
    __shared__ float sm_d[4][4][64];
    __shared__ float sm_m[4][4][64];
    const float* WihT = T + 15360;    // [64][192]
    const float* WhhT = T + 27648;    // [64][192]
    int w = threadIdx.x >> 6, lane = threadIdx.x & 63;
    int n0 = blockIdx.x * 16 + w * 4;
    if (n0 >= NN) return;             // NN%4==0 -> a wave's 4 nodes all valid or none

    float hv[4], dv[4], m[4];
    #pragma unroll
    for (int j = 0; j < 4; ++j) {
        size_t idx = (size_t)(n0 + j) * 64 + lane;
        hv[j] = hbuf[idx];
        dv[j] = hid[idx];
        sm_h[w][j][lane] = hv[j];
        sm_d[w][j][lane] = dv[j];
        m[j] = aggr[idx] + cbias[lane];
    }

    // m += h @ root   (root row i reused by 4 nodes)
    for (int i = 0; i < 64; i += 4) {
        float4 bb[4];
        #pragma unroll
        for (int j = 0; j < 4; ++j) bb[j] = *(const float4*)&sm_h[w][j][i];
        #pragma unroll
        for (int ii = 0; ii < 4; ++ii) {
            float rv = root[(i + ii) * 64 + lane];
            #pragma unroll
            for (int j = 0; j < 4; ++j)
                m[j] += ((const float*)&bb[j])[ii] * rv;
        }
    }
    #pragma unroll
    for (int j = 0; j < 4; ++j) sm_m[w][j][lane] = m[j];

    float gr[4], gz[4], gn[4], hr[4], hz[4], hn[4];
    #pragma unroll
    for (int j = 0; j < 4; ++j) {
        gr[j] = bih[lane]; gz[j] = bih[64 + lane]; gn[j] = bih[128 + lane];
        hr[j] = bhh[lane]; hz[j] = bhh[64 + lane]; hn[j] = bhh[128 + lane];
    }
    for (int i = 0; i < 64; i += 4) {
        float4 bm[4], bd[4];
        #pragma unroll
        for (int j = 0; j < 4; ++j) {
            bm[j] = *(const float4*)&sm_m[w][j][i];
            bd[j] = *(const float4*)&sm_d[w][j][i];
        }
        #pragma unroll
        for (int ii = 0; ii < 4; ++ii) {
            float wr = WihT[(i + ii) * 192 + lane];
            float wz = WihT[(i + ii) * 192 + 64 + lane];
            float wn = WihT[(i + ii) * 192 + 128 + lane];
            float vr = WhhT[(i + ii) * 192 + lane];
            float vz = WhhT[(i + ii) * 192 + 64 + lane];
            float vn = WhhT[(i + ii) * 192 + 128 + lane];
            #pragma unroll
            for (int j = 0; j < 4; ++j) {
                float mv = ((const float*)&bm[j])[ii];
                float dvv = ((const float*)&bd[j])[ii];
                gr[j] += mv * wr; gz[j] += mv * wz; gn[j] += mv * wn;
                hr[j] += dvv * vr; hz[j] += dvv * vz; hn[j] += dvv * vn;
            }
        }
    }

    #pragma unroll
    for (int j = 0; j < 4; ++j) {
        float r  = 1.f / (1.f + expf(-(gr[j] + hr[j])));
        float z  = 1.f / (1.f + expf(-(gz[j] + hz[j])));
        float nv = tanhf(gn[j] + r * hn[j]);
        float outv = (1.f - z) * nv + z * dv[j];
        size_t idx = (size_t)(n0 + j) * 64 + lane;
        hbuf[idx] = outv;
        hid[idx]  = outv;
        h16[idx]  = (f16)outv;
        if (out2) out2[idx] = outv;
    }
}

extern "C" void kernel_launch(void* const* d_in, const int* in_sizes, int n_in,
                              void* d_out, int out_size, void* d_ws, size_t ws_size,
                              hipStream_t stream)
{
    const float* x   = (const float*)d_in[0];
    const float* ea  = (const float*)d_in[1];
    const float* Wn1 = (const float*)d_in[2];  const float* bn1 = (const float*)d_in[3];
    const float* Wn2 = (const float*)d_in[4];  const float* bn2 = (const float*)d_in[5];
    const float* Wn3 = (const float*)d_in[6];  const float* bn3 = (const float*)d_in[7];
    const float* We1 = (const float*)d_in[8];  const float* be1 = (const float*)d_in[9];
    const float* We2 = (const float*)d_in[10]; const float* be2 = (const float*)d_in[11];
    const float* We3 = (const float*)d_in[12]; const float* be3 = (const float*)d_in[13];
    const float* roots = (const float*)d_in[14];
    const float* cb    = (const float*)d_in[15];
    const float* Wih = (const float*)d_in[16]; const float* Whh = (const float*)d_in[17];
    const float* bih = (const float*)d_in[18]; const float* bhh = (const float*)d_in[19];
    const int*   ei  = (const int*)d_in[20];

    // ws layout: fp32 region then fp16 region (16B-aligned), ~35.9 MB total
    float* ws   = (float*)d_ws;
    float* hbuf = ws;                               // N*64
    float* hid  = hbuf + (size_t)NN * 64;           // N*64
    float* aggr = hid  + (size_t)NN * 64;           // N*64
    float* Tbuf = aggr + (size_t)NN * 64;           // 39936 (pad to 40960)
    f16*   h16  = (f16*)(ws + 3 * (size_t)NN * 64 + 40960);   // N*64
    f16*   ew16 = h16  + (size_t)NN * 64;                     // E*64
    f16*   Wf16 = ew16 + (size_t)NE * 64;                     // 65*4096

    prep_t <<<(39936 + 255) / 256, 256, 0, stream>>>(Wn1, Wn2, Wn3, We1, We2, Wih, Whh, Tbuf);
    wf_prep<<<(266240 + 255) / 256, 256, 0, stream>>>(We3, be3, Wf16);
    node_mlp<<<(NN + 3) / 4, 256, 0, stream>>>(x, Tbuf, bn1, bn2, bn3, hbuf, h16);
    edge_mlp<<<(NE + 3) / 4, 256, 0, stream>>>(ea, Tbuf, be1, be2, ew16);
    hipMemsetAsync(hid, 0, (size_t)NN * 64 * sizeof(float), stream);

    for (int l = 0; l < 3; ++l) {
        hipMemsetAsync(aggr, 0, (size_t)NN * 64 * sizeof(float), stream);
        msg_mfma<<<(NE + 127) / 128, 256, 0, stream>>>(h16, ew16, Wf16, ei, aggr);
        gru_kernel<<<(NN + 15) / 16, 256, 0, stream>>>(aggr, hbuf, hid, h16,
            roots + (size_t)l * 4096, cb + (size_t)l * 64,
            Tbuf, bih, bhh, (l == 2) ? (float*)d_out : nullptr);
    }
}

// Round 6
// 529.214 us; speedup vs baseline: 7.0934x; 2.0154x over previous
//
#include <hip/hip_runtime.h>
#include <math.h>

#define NN 25000
#define NE 100000

typedef _Float16 f16;
typedef _Float16 half8 __attribute__((ext_vector_type(8)));
typedef float f32x4 __attribute__((ext_vector_type(4)));

// ---------------- one-time weight prep ----------------
// Wf16: 65 K-slabs of [64 o][64 k] fp16. Slabs 0..63 are We3 rows verbatim
// (We3[(i*64+o)][k] is already [i][o][k] order); slab 64 is be3 transposed.
__global__ __launch_bounds__(256) void wf_prep(const float* __restrict__ We3,
                                               const float* __restrict__ be3,
                                               f16* __restrict__ Wf16)
{
    int f = blockIdx.x * 256 + threadIdx.x;          // 0 .. 266239
    if (f >= 266240) return;
    if (f < 262144) Wf16[f] = (f16)We3[f];
    else {
        int j = f - 262144; int o = (j >> 6), k = j & 63;
        Wf16[f] = (f16)be3[k * 64 + o];
    }
}

// transposed fp32 weights so per-lane reads are coalesced (lane = out index)
__global__ __launch_bounds__(256) void prep_t(
    const float* __restrict__ Wn1, const float* __restrict__ Wn2,
    const float* __restrict__ Wn3, const float* __restrict__ We1,
    const float* __restrict__ We2, const float* __restrict__ Wih,
    const float* __restrict__ Whh, float* __restrict__ T)
{
    int f = blockIdx.x * 256 + threadIdx.x;
    if (f >= 39936) return;
    if (f < 2048)       { int j = f;         T[f] = Wn1[(j & 63) * 32 + (j >> 6)]; }
    else if (f < 6144)  { int j = f - 2048;  T[f] = Wn2[(j & 63) * 64 + (j >> 6)]; }
    else if (f < 10240) { int j = f - 6144;  T[f] = Wn3[(j & 63) * 64 + (j >> 6)]; }
    else if (f < 11264) { int j = f - 10240; T[f] = We1[(j & 63) * 16 + (j >> 6)]; }
    else if (f < 15360) { int j = f - 11264; T[f] = We2[(j & 63) * 64 + (j >> 6)]; }
    else if (f < 27648) { int j = f - 15360; T[f] = Wih[(j % 192) * 64 + (j / 192)]; }
    else                { int j = f - 27648; T[f] = Whh[(j % 192) * 64 + (j / 192)]; }
}

// ---------------- node MLP ----------------
__global__ __launch_bounds__(256) void node_mlp(
    const float* __restrict__ x, const float* __restrict__ T,
    const float* __restrict__ bn1, const float* __restrict__ bn2,
    const float* __restrict__ bn3,
    float* __restrict__ h0, f16* __restrict__ h16)
{
    __shared__ float sx[4][32];
    __shared__ float sh1[4][64];
    const float* Wn1T = T;            // [32][64]
    const float* Wn2T = T + 2048;     // [64][64]
    const float* Wn3T = T + 6144;     // [64][64]
    int w = threadIdx.x >> 6, lane = threadIdx.x & 63;
    int n = blockIdx.x * 4 + w;
    if (n >= NN) return;                      // wave-private LDS slice, no barriers
    if (lane < 32) sx[w][lane] = x[(size_t)n * 32 + lane];
    float a = bn1[lane];
    #pragma unroll
    for (int i = 0; i < 32; ++i) a += sx[w][i] * Wn1T[i * 64 + lane];
    a = fmaxf(a, 0.f);
    sh1[w][lane] = a;
    float b = bn2[lane];
    #pragma unroll
    for (int i = 0; i < 64; ++i) b += sh1[w][i] * Wn2T[i * 64 + lane];
    b = fmaxf(b, 0.f);
    sh1[w][lane] = b;
    float c = bn3[lane];
    #pragma unroll
    for (int i = 0; i < 64; ++i) c += sh1[w][i] * Wn3T[i * 64 + lane];
    size_t idx = (size_t)n * 64 + lane;
    h0[idx] = c;
    h16[idx] = (f16)c;
}

// ---------------- edge MLP (2 layers) -> fp16 ----------------
__global__ __launch_bounds__(256) void edge_mlp(
    const float* __restrict__ ea, const float* __restrict__ T,
    const float* __restrict__ be1, const float* __restrict__ be2,
    f16* __restrict__ ew16)
{
    __shared__ float sa[4][16];
    __shared__ float st[4][64];
    const float* We1T = T + 10240;    // [16][64]
    const float* We2T = T + 11264;    // [64][64]
    int w = threadIdx.x >> 6, lane = threadIdx.x & 63;
    int e = blockIdx.x * 4 + w;
    if (e >= NE) return;
    if (lane < 16) sa[w][lane] = ea[(size_t)e * 16 + lane];
    float a = be1[lane];
    #pragma unroll
    for (int i = 0; i < 16; ++i) a += sa[w][i] * We1T[i * 64 + lane];
    a = fmaxf(a, 0.f);
    st[w][lane] = a;
    float b = be2[lane];
    #pragma unroll
    for (int i = 0; i < 64; ++i) b += st[w][i] * We2T[i * 64 + lane];
    ew16[(size_t)e * 64 + lane] = (f16)fmaxf(b, 0.f);
}

// ---------------- message GEMM (MFMA f16) + scatter ----------------
// msg[E,64] = P[E,4160] @ [Wf16; be3T], P[e, i*64+k] = h16[src_e,i]*ew16[e,k].
// Block = 128 edges x 64 outs, 4 waves; wave = 32 edges (2 M-subtiles).
// B slabs (8KB each) staged in LDS once per block, double-buffered, via
// T14 reg-staging: global loads for slab i+2 issued at slab i, ds_write at
// slab i+1 -> L2 latency hides under a full slab of compute.
// ds_write dest AND ds_read addr XOR-swizzled (d ^= ((d>>7)&7)<<4): the
// 128B-row-stride frag reads would otherwise be a 16-way bank conflict.
// A-fragments ev* are K-invariant -> hoisted to registers; hs batched x8.
__global__ __launch_bounds__(256) void msg_mfma(
    const f16* __restrict__ h16, const f16* __restrict__ ew16,
    const f16* __restrict__ Wf16, const int* __restrict__ edge_index,
    float* __restrict__ aggr)
{
    __shared__ f16 sh_h[128][72];
    __shared__ f16 sh_e[128][72];
    __shared__ f16 sh_b[2][4096];    // 2 x 8KB B-slab double buffer (swizzled)
    __shared__ int sh_dst[128];
    int t = threadIdx.x;
    int e0 = blockIdx.x * 128;
    int lane = t & 63, wv = t >> 6;

    {   // gather-stage 128 h-rows + 128 ew-rows as fp16; 2 threads/row
        int row = t >> 1, part = t & 1;
        int e = e0 + row;
        bool valid = e < NE;
        int ec = valid ? e : NE - 1;
        int src = edge_index[ec];
        const f16* hp = h16 + (size_t)src * 64 + part * 32;
        const f16* ep = ew16 + (size_t)ec * 64 + part * 32;
        uint4 z = make_uint4(0u, 0u, 0u, 0u);
        uint4 h0 = valid ? *(const uint4*)hp : z;
        uint4 h1 = valid ? *(const uint4*)(hp + 8) : z;
        uint4 h2 = valid ? *(const uint4*)(hp + 16) : z;
        uint4 h3 = valid ? *(const uint4*)(hp + 24) : z;
        uint4 g0 = valid ? *(const uint4*)ep : z;
        uint4 g1 = valid ? *(const uint4*)(ep + 8) : z;
        uint4 g2 = valid ? *(const uint4*)(ep + 16) : z;
        uint4 g3 = valid ? *(const uint4*)(ep + 24) : z;
        *(uint4*)&sh_h[row][part * 32]      = h0;
        *(uint4*)&sh_h[row][part * 32 + 8]  = h1;
        *(uint4*)&sh_h[row][part * 32 + 16] = h2;
        *(uint4*)&sh_h[row][part * 32 + 24] = h3;
        *(uint4*)&sh_e[row][part * 32]      = g0;
        *(uint4*)&sh_e[row][part * 32 + 8]  = g1;
        *(uint4*)&sh_e[row][part * 32 + 16] = g2;
        *(uint4*)&sh_e[row][part * 32 + 24] = g3;
        if (t < 128) sh_dst[t] = (e0 + t < NE) ? edge_index[NE + e0 + t] : -1;
    }

    // ---- B-slab staging helpers (thread t owns bytes t*16 of each 4KB half)
    char* bflat = (char*)&sh_b[0][0];
    const uint4* gW = (const uint4*)Wf16;            // 512 uint4 per slab
    int d0 = t * 16, d1 = 4096 + t * 16;
    int dsw0 = d0 ^ (((d0 >> 7) & 7) << 4);
    int dsw1 = d1 ^ (((d1 >> 7) & 7) << 4);

    // prologue: slab 0 -> regs -> buf0 ; issue slab 1 -> regs
    uint4 r0 = gW[t], r1 = gW[256 + t];
    *(uint4*)(bflat + dsw0) = r0;
    *(uint4*)(bflat + dsw1) = r1;
    r0 = gW[512 + t]; r1 = gW[512 + 256 + t];
    __syncthreads();                                  // gather + slab0 visible

    int r16 = lane & 15, kq = lane >> 4;
    int row0 = wv * 32 + r16, row1 = row0 + 16;
    f32x4 acc[2][4];
    #pragma unroll
    for (int m = 0; m < 2; ++m)
        #pragma unroll
        for (int n = 0; n < 4; ++n) acc[m][n] = (f32x4){0,0,0,0};

    // K-invariant A-operand halves (ew rows), hoisted to registers
    half8 evA0 = *(const half8*)&sh_e[row0][kq * 8];
    half8 evA1 = *(const half8*)&sh_e[row0][32 + kq * 8];
    half8 evB0 = *(const half8*)&sh_e[row1][kq * 8];
    half8 evB1 = *(const half8*)&sh_e[row1][32 + kq * 8];

    // swizzled per-lane B-frag base offsets (row stride 128B, +swizzle)
    int swzA = (kq << 4) ^ ((r16 & 7) << 4);          // k 0..31 half
    int swzB = ((kq << 4) | 64) ^ ((r16 & 7) << 4);   // k 32..63 half
    const char* pB = bflat + r16 * 128;

    for (int i8 = 0; i8 < 8; ++i8) {
        half8 hA = *(const half8*)&sh_h[row0][i8 * 8];
        half8 hB = *(const half8*)&sh_h[row1][i8 * 8];
        #pragma unroll
        for (int ii = 0; ii < 8; ++ii) {
            const int i = i8 * 8 + ii;
            const int buf = ii & 1;                   // i8*8 even -> i&1 == ii&1
            const char* bb = pB + buf * 8192;
            half8 b00 = *(const half8*)(bb + 0    + swzA);
            half8 b01 = *(const half8*)(bb + 0    + swzB);
            half8 b10 = *(const half8*)(bb + 2048 + swzA);
            half8 b11 = *(const half8*)(bb + 2048 + swzB);
            half8 b20 = *(const half8*)(bb + 4096 + swzA);
            half8 b21 = *(const half8*)(bb + 4096 + swzB);
            half8 b30 = *(const half8*)(bb + 6144 + swzA);
            half8 b31 = *(const half8*)(bb + 6144 + swzB);
            half8 aA0 = evA0 * hA[ii];
            half8 aA1 = evA1 * hA[ii];
            half8 aB0 = evB0 * hB[ii];
            half8 aB1 = evB1 * hB[ii];
            acc[0][0] = __builtin_amdgcn_mfma_f32_16x16x32_f16(aA0, b00, acc[0][0], 0, 0, 0);
            acc[0][0] = __builtin_amdgcn_mfma_f32_16x16x32_f16(aA1, b01, acc[0][0], 0, 0, 0);
            acc[0][1] = __builtin_amdgcn_mfma_f32_16x16x32_f16(aA0, b10, acc[0][1], 0, 0, 0);
            acc[0][1] = __builtin_amdgcn_mfma_f32_16x16x32_f16(aA1, b11, acc[0][1], 0, 0, 0);
            acc[0][2] = __builtin_amdgcn_mfma_f32_16x16x32_f16(aA0, b20, acc[0][2], 0, 0, 0);
            acc[0][2] = __builtin_amdgcn_mfma_f32_16x16x32_f16(aA1, b21, acc[0][2], 0, 0, 0);
            acc[0][3] = __builtin_amdgcn_mfma_f32_16x16x32_f16(aA0, b30, acc[0][3], 0, 0, 0);
            acc[0][3] = __builtin_amdgcn_mfma_f32_16x16x32_f16(aA1, b31, acc[0][3], 0, 0, 0);
            acc[1][0] = __builtin_amdgcn_mfma_f32_16x16x32_f16(aB0, b00, acc[1][0], 0, 0, 0);
            acc[1][0] = __builtin_amdgcn_mfma_f32_16x16x32_f16(aB1, b01, acc[1][0], 0, 0, 0);
            acc[1][1] = __builtin_amdgcn_mfma_f32_16x16x32_f16(aB0, b10, acc[1][1], 0, 0, 0);
            acc[1][1] = __builtin_amdgcn_mfma_f32_16x16x32_f16(aB1, b11, acc[1][1], 0, 0, 0);
            acc[1][2] = __builtin_amdgcn_mfma_f32_16x16x32_f16(aB0, b20, acc[1][2], 0, 0, 0);
            acc[1][2] = __builtin_amdgcn_mfma_f32_16x16x32_f16(aB1, b21, acc[1][2], 0, 0, 0);
            acc[1][3] = __builtin_amdgcn_mfma_f32_16x16x32_f16(aB0, b30, acc[1][3], 0, 0, 0);
            acc[1][3] = __builtin_amdgcn_mfma_f32_16x16x32_f16(aB1, b31, acc[1][3], 0, 0, 0);

            // stage: write slab i+1 (in regs) into the other buffer,
            // then issue global loads for slab i+2
            {
                char* wb = bflat + (buf ^ 1) * 8192;
                *(uint4*)(wb + dsw0) = r0;
                *(uint4*)(wb + dsw1) = r1;
                if (i < 63) {
                    size_t sb = (size_t)(i + 2) * 512;
                    r0 = gW[sb + t];
                    r1 = gW[sb + 256 + t];
                }
            }
            __syncthreads();
        }
    }

    {   // bias slab (i=64, in buf0): A = h16 rows directly, B = be3T
        const char* bb = pB;                          // buf 0
        half8 b00 = *(const half8*)(bb + 0    + swzA);
        half8 b01 = *(const half8*)(bb + 0    + swzB);
        half8 b10 = *(const half8*)(bb + 2048 + swzA);
        half8 b11 = *(const half8*)(bb + 2048 + swzB);
        half8 b20 = *(const half8*)(bb + 4096 + swzA);
        half8 b21 = *(const half8*)(bb + 4096 + swzB);
        half8 b30 = *(const half8*)(bb + 6144 + swzA);
        half8 b31 = *(const half8*)(bb + 6144 + swzB);
        half8 aA0 = *(const half8*)&sh_h[row0][kq * 8];
        half8 aA1 = *(const half8*)&sh_h[row0][32 + kq * 8];
        half8 aB0 = *(const half8*)&sh_h[row1][kq * 8];
        half8 aB1 = *(const half8*)&sh_h[row1][32 + kq * 8];
        acc[0][0] = __builtin_amdgcn_mfma_f32_16x16x32_f16(aA0, b00, acc[0][0], 0, 0, 0);
        acc[0][0] = __builtin_amdgcn_mfma_f32_16x16x32_f16(aA1, b01, acc[0][0], 0, 0, 0);
        acc[0][1] = __builtin_amdgcn_mfma_f32_16x16x32_f16(aA0, b10, acc[0][1], 0, 0, 0);
        acc[0][1] = __builtin_amdgcn_mfma_f32_16x16x32_f16(aA1, b11, acc[0][1], 0, 0, 0);
        acc[0][2] = __builtin_amdgcn_mfma_f32_16x16x32_f16(aA0, b20, acc[0][2], 0, 0, 0);
        acc[0][2] = __builtin_amdgcn_mfma_f32_16x16x32_f16(aA1, b21, acc[0][2], 0, 0, 0);
        acc[0][3] = __builtin_amdgcn_mfma_f32_16x16x32_f16(aA0, b30, acc[0][3], 0, 0, 0);
        acc[0][3] = __builtin_amdgcn_mfma_f32_16x16x32_f16(aA1, b31, acc[0][3], 0, 0, 0);
        acc[1][0] = __builtin_amdgcn_mfma_f32_16x16x32_f16(aB0, b00, acc[1][0], 0, 0, 0);
        acc[1][0] = __builtin_amdgcn_mfma_f32_16x16x32_f16(aB1, b01, acc[1][0], 0, 0, 0);
        acc[1][1] = __builtin_amdgcn_mfma_f32_16x16x32_f16(aB0, b10, acc[1][1], 0, 0, 0);
        acc[1][1] = __builtin_amdgcn_mfma_f32_16x16x32_f16(aB1, b11, acc[1][1], 0, 0, 0);
        acc[1][2] = __builtin_amdgcn_mfma_f32_16x16x32_f16(aB0, b20, acc[1][2], 0, 0, 0);
        acc[1][2] = __builtin_amdgcn_mfma_f32_16x16x32_f16(aB1, b21, acc[1][2], 0, 0, 0);
        acc[1][3] = __builtin_amdgcn_mfma_f32_16x16x32_f16(aB0, b30, acc[1][3], 0, 0, 0);
        acc[1][3] = __builtin_amdgcn_mfma_f32_16x16x32_f16(aB1, b31, acc[1][3], 0, 0, 0);
    }

    // scatter: C/D layout col=lane&15, row=(lane>>4)*4+reg  [m89-verified]
    #pragma unroll
    for (int m = 0; m < 2; ++m) {
        #pragma unroll
        for (int reg = 0; reg < 4; ++reg) {
            int e_l = wv * 32 + m * 16 + kq * 4 + reg;
            int d = sh_dst[e_l];
            if (d >= 0) {
                float* ap = aggr + (size_t)d * 64 + r16;
                atomicAdd(ap,      acc[m][0][reg]);
                atomicAdd(ap + 16, acc[m][1][reg]);
                atomicAdd(ap + 32, acc[m][2][reg]);
                atomicAdd(ap + 48, acc[m][3][reg]);
            }
        }
    }
}

// ---------------- fused root-term + GRU step: 4 nodes per wave ----------------
__global__ __launch_bounds__(256) void gru_kernel(
    const float* __restrict__ aggr, float* __restrict__ hbuf, float* __restrict__ hid,
    f16* __restrict__ h16,
    const float* __restrict__ root, const float* __restrict__ cbias,
    const float* __restrict__ T,
    const float* __restrict__ bih, const float* __restrict__ bhh,
    float* __restrict__ out2)
{
    __shared__ float sm_h[4][4][64];
    __shared__ float sm_d[4][4][64];
    __shared__ float sm_m[4][4][64];
    const float* WihT = T + 15360;    // [64][192]
    const float* WhhT = T + 27648;    // [64][192]
    int w = threadIdx.x >> 6, lane = threadIdx.x & 63;
    int n0 = blockIdx.x * 16 + w * 4;
    if (n0 >= NN) return;             // NN%4==0 -> a wave's 4 nodes all valid or none

    float hv[4], dv[4], m[4];
    #pragma unroll
    for (int j = 0; j < 4; ++j) {
        size_t idx = (size_t)(n0 + j) * 64 + lane;
        hv[j] = hbuf[idx];
        dv[j] = hid[idx];
        sm_h[w][j][lane] = hv[j];
        sm_d[w][j][lane] = dv[j];
        m[j] = aggr[idx] + cbias[lane];
    }

    // m += h @ root   (root row i reused by 4 nodes)
    for (int i = 0; i < 64; i += 4) {
        float4 bb[4];
        #pragma unroll
        for (int j = 0; j < 4; ++j) bb[j] = *(const float4*)&sm_h[w][j][i];
        #pragma unroll
        for (int ii = 0; ii < 4; ++ii) {
            float rv = root[(i + ii) * 64 + lane];
            #pragma unroll
            for (int j = 0; j < 4; ++j)
                m[j] += ((const float*)&bb[j])[ii] * rv;
        }
    }
    #pragma unroll
    for (int j = 0; j < 4; ++j) sm_m[w][j][lane] = m[j];

    float gr[4], gz[4], gn[4], hr[4], hz[4], hn[4];
    #pragma unroll
    for (int j = 0; j < 4; ++j) {
        gr[j] = bih[lane]; gz[j] = bih[64 + lane]; gn[j] = bih[128 + lane];
        hr[j] = bhh[lane]; hz[j] = bhh[64 + lane]; hn[j] = bhh[128 + lane];
    }
    for (int i = 0; i < 64; i += 4) {
        float4 bm[4], bd[4];
        #pragma unroll
        for (int j = 0; j < 4; ++j) {
            bm[j] = *(const float4*)&sm_m[w][j][i];
            bd[j] = *(const float4*)&sm_d[w][j][i];
        }
        #pragma unroll
        for (int ii = 0; ii < 4; ++ii) {
            float wr = WihT[(i + ii) * 192 + lane];
            float wz = WihT[(i + ii) * 192 + 64 + lane];
            float wn = WihT[(i + ii) * 192 + 128 + lane];
            float vr = WhhT[(i + ii) * 192 + lane];
            float vz = WhhT[(i + ii) * 192 + 64 + lane];
            float vn = WhhT[(i + ii) * 192 + 128 + lane];
            #pragma unroll
            for (int j = 0; j < 4; ++j) {
                float mv = ((const float*)&bm[j])[ii];
                float dvv = ((const float*)&bd[j])[ii];
                gr[j] += mv * wr; gz[j] += mv * wz; gn[j] += mv * wn;
                hr[j] += dvv * vr; hz[j] += dvv * vz; hn[j] += dvv * vn;
            }
        }
    }

    #pragma unroll
    for (int j = 0; j < 4; ++j) {
        float r  = 1.f / (1.f + expf(-(gr[j] + hr[j])));
        float z  = 1.f / (1.f + expf(-(gz[j] + hz[j])));
        float nv = tanhf(gn[j] + r * hn[j]);
        float outv = (1.f - z) * nv + z * dv[j];
        size_t idx = (size_t)(n0 + j) * 64 + lane;
        hbuf[idx] = outv;
        hid[idx]  = outv;
        h16[idx]  = (f16)outv;
        if (out2) out2[idx] = outv;
    }
}

extern "C" void kernel_launch(void* const* d_in, const int* in_sizes, int n_in,
                              void* d_out, int out_size, void* d_ws, size_t ws_size,
                              hipStream_t stream)
{
    const float* x   = (const float*)d_in[0];
    const float* ea  = (const float*)d_in[1];
    const float* Wn1 = (const float*)d_in[2];  const float* bn1 = (const float*)d_in[3];
    const float* Wn2 = (const float*)d_in[4];  const float* bn2 = (const float*)d_in[5];
    const float* Wn3 = (const float*)d_in[6];  const float* bn3 = (const float*)d_in[7];
    const float* We1 = (const float*)d_in[8];  const float* be1 = (const float*)d_in[9];
    const float* We2 = (const float*)d_in[10]; const float* be2 = (const float*)d_in[11];
    const float* We3 = (const float*)d_in[12]; const float* be3 = (const float*)d_in[13];
    const float* roots = (const float*)d_in[14];
    const float* cb    = (const float*)d_in[15];
    const float* Wih = (const float*)d_in[16]; const float* Whh = (const float*)d_in[17];
    const float* bih = (const float*)d_in[18]; const float* bhh = (const float*)d_in[19];
    const int*   ei  = (const int*)d_in[20];

    // ws layout: fp32 region then fp16 region (16B-aligned), ~35.9 MB total
    float* ws   = (float*)d_ws;
    float* hbuf = ws;                               // N*64
    float* hid  = hbuf + (size_t)NN * 64;           // N*64
    float* aggr = hid  + (size_t)NN * 64;           // N*64
    float* Tbuf = aggr + (size_t)NN * 64;           // 39936 (pad to 40960)
    f16*   h16  = (f16*)(ws + 3 * (size_t)NN * 64 + 40960);   // N*64
    f16*   ew16 = h16  + (size_t)NN * 64;                     // E*64
    f16*   Wf16 = ew16 + (size_t)NE * 64;                     // 65*4096

    prep_t <<<(39936 + 255) / 256, 256, 0, stream>>>(Wn1, Wn2, Wn3, We1, We2, Wih, Whh, Tbuf);
    wf_prep<<<(266240 + 255) / 256, 256, 0, stream>>>(We3, be3, Wf16);
    node_mlp<<<(NN + 3) / 4, 256, 0, stream>>>(x, Tbuf, bn1, bn2, bn3, hbuf, h16);
    edge_mlp<<<(NE + 3) / 4, 256, 0, stream>>>(ea, Tbuf, be1, be2, ew16);
    hipMemsetAsync(hid, 0, (size_t)NN * 64 * sizeof(float), stream);

    for (int l = 0; l < 3; ++l) {
        hipMemsetAsync(aggr, 0, (size_t)NN * 64 * sizeof(float), stream);
        msg_mfma<<<(NE + 127) / 128, 256, 0, stream>>>(h16, ew16, Wf16, ei, aggr);
        gru_kernel<<<(NN + 15) / 16, 256, 0, stream>>>(aggr, hbuf, hid, h16,
            roots + (size_t)l * 4096, cb + (size_t)l * 64,
            Tbuf, bih, bhh, (l == 2) ? (float*)d_out : nullptr);
    }
}

// Round 7
// 462.880 us; speedup vs baseline: 8.1100x; 1.1433x over previous
//
#include <hip/hip_runtime.h>
#include <math.h>

#define NN 25000
#define NE 100000

typedef _Float16 f16;
typedef _Float16 half8 __attribute__((ext_vector_type(8)));
typedef float f32x4 __attribute__((ext_vector_type(4)));

// ---------------- one-time weight prep (merged) ----------------
// [0, 39936): transposed fp32 weights T ; [39936, 306176): Wf16 (65 slabs of
// [64 o][64 k] fp16; slabs 0..63 = We3 verbatim, slab 64 = be3 transposed).
__global__ __launch_bounds__(256) void prep_all(
    const float* __restrict__ Wn1, const float* __restrict__ Wn2,
    const float* __restrict__ Wn3, const float* __restrict__ We1,
    const float* __restrict__ We2, const float* __restrict__ Wih,
    const float* __restrict__ Whh, const float* __restrict__ We3,
    const float* __restrict__ be3, float* __restrict__ T,
    f16* __restrict__ Wf16)
{
    int f = blockIdx.x * 256 + threadIdx.x;          // 0 .. 306175
    if (f < 39936) {
        if (f < 2048)       { int j = f;         T[f] = Wn1[(j & 63) * 32 + (j >> 6)]; }
        else if (f < 6144)  { int j = f - 2048;  T[f] = Wn2[(j & 63) * 64 + (j >> 6)]; }
        else if (f < 10240) { int j = f - 6144;  T[f] = Wn3[(j & 63) * 64 + (j >> 6)]; }
        else if (f < 11264) { int j = f - 10240; T[f] = We1[(j & 63) * 16 + (j >> 6)]; }
        else if (f < 15360) { int j = f - 11264; T[f] = We2[(j & 63) * 64 + (j >> 6)]; }
        else if (f < 27648) { int j = f - 15360; T[f] = Wih[(j % 192) * 64 + (j / 192)]; }
        else                { int j = f - 27648; T[f] = Whh[(j % 192) * 64 + (j / 192)]; }
    } else {
        int g = f - 39936;                           // 0 .. 266239
        if (g < 262144) Wf16[g] = (f16)We3[g];
        else {
            int j = g - 262144; int o = (j >> 6), k = j & 63;
            Wf16[g] = (f16)be3[k * 64 + o];
        }
    }
}

// ---------------- node MLP: 8 nodes per wave (weights reused x8) ----------------
__global__ __launch_bounds__(256) void node_mlp(
    const float* __restrict__ x, const float* __restrict__ T,
    const float* __restrict__ bn1, const float* __restrict__ bn2,
    const float* __restrict__ bn3,
    float* __restrict__ hbuf, f16* __restrict__ h16, float* __restrict__ aggr)
{
    __shared__ float sx[4][8][32];
    __shared__ float sh1[4][8][64];
    const float* Wn1T = T;            // [32][64]
    const float* Wn2T = T + 2048;     // [64][64]
    const float* Wn3T = T + 6144;     // [64][64]
    int w = threadIdx.x >> 6, lane = threadIdx.x & 63;
    int n0 = blockIdx.x * 32 + w * 8;
    if (n0 >= NN) return;             // NN%8==0 -> wave's 8 nodes all valid or none
    #pragma unroll
    for (int jj = 0; jj < 4; ++jj) {  // 8 nodes x 32 floats = 4 per lane
        int f = jj * 64 + lane;
        sx[w][f >> 5][f & 31] = x[(size_t)(n0 + (f >> 5)) * 32 + (f & 31)];
    }
    float a[8];
    #pragma unroll
    for (int j = 0; j < 8; ++j) a[j] = bn1[lane];
    for (int i = 0; i < 32; i += 4) {
        float4 bb[8];
        #pragma unroll
        for (int j = 0; j < 8; ++j) bb[j] = *(const float4*)&sx[w][j][i];
        #pragma unroll
        for (int ii = 0; ii < 4; ++ii) {
            float wv = Wn1T[(i + ii) * 64 + lane];
            #pragma unroll
            for (int j = 0; j < 8; ++j) a[j] += ((const float*)&bb[j])[ii] * wv;
        }
    }
    #pragma unroll
    for (int j = 0; j < 8; ++j) { sh1[w][j][lane] = fmaxf(a[j], 0.f); a[j] = bn2[lane]; }
    for (int i = 0; i < 64; i += 4) {
        float4 bb[8];
        #pragma unroll
        for (int j = 0; j < 8; ++j) bb[j] = *(const float4*)&sh1[w][j][i];
        #pragma unroll
        for (int ii = 0; ii < 4; ++ii) {
            float wv = Wn2T[(i + ii) * 64 + lane];
            #pragma unroll
            for (int j = 0; j < 8; ++j) a[j] += ((const float*)&bb[j])[ii] * wv;
        }
    }
    // in-wave: all reads of sh1 above complete (program order) before overwrite
    #pragma unroll
    for (int j = 0; j < 8; ++j) { sh1[w][j][lane] = fmaxf(a[j], 0.f); a[j] = bn3[lane]; }
    for (int i = 0; i < 64; i += 4) {
        float4 bb[8];
        #pragma unroll
        for (int j = 0; j < 8; ++j) bb[j] = *(const float4*)&sh1[w][j][i];
        #pragma unroll
        for (int ii = 0; ii < 4; ++ii) {
            float wv = Wn3T[(i + ii) * 64 + lane];
            #pragma unroll
            for (int j = 0; j < 8; ++j) a[j] += ((const float*)&bb[j])[ii] * wv;
        }
    }
    #pragma unroll
    for (int j = 0; j < 8; ++j) {
        size_t idx = (size_t)(n0 + j) * 64 + lane;
        hbuf[idx] = a[j];
        h16[idx]  = (f16)a[j];
        aggr[idx] = 0.f;              // zero aggr for layer 0 (no memset launch)
    }
}

// ---------------- edge MLP: 8 edges per wave ----------------
__global__ __launch_bounds__(256) void edge_mlp(
    const float* __restrict__ ea, const float* __restrict__ T,
    const float* __restrict__ be1, const float* __restrict__ be2,
    f16* __restrict__ ew16)
{
    __shared__ float sa[4][8][16];
    __shared__ float st[4][8][64];
    const float* We1T = T + 10240;    // [16][64]
    const float* We2T = T + 11264;    // [64][64]
    int w = threadIdx.x >> 6, lane = threadIdx.x & 63;
    int e0 = blockIdx.x * 32 + w * 8;
    if (e0 >= NE) return;             // NE%32==0
    #pragma unroll
    for (int jj = 0; jj < 2; ++jj) {  // 8 edges x 16 floats = 2 per lane
        int f = jj * 64 + lane;
        sa[w][f >> 4][f & 15] = ea[(size_t)(e0 + (f >> 4)) * 16 + (f & 15)];
    }
    float a[8];
    #pragma unroll
    for (int j = 0; j < 8; ++j) a[j] = be1[lane];
    for (int i = 0; i < 16; i += 4) {
        float4 bb[8];
        #pragma unroll
        for (int j = 0; j < 8; ++j) bb[j] = *(const float4*)&sa[w][j][i];
        #pragma unroll
        for (int ii = 0; ii < 4; ++ii) {
            float wv = We1T[(i + ii) * 64 + lane];
            #pragma unroll
            for (int j = 0; j < 8; ++j) a[j] += ((const float*)&bb[j])[ii] * wv;
        }
    }
    #pragma unroll
    for (int j = 0; j < 8; ++j) { st[w][j][lane] = fmaxf(a[j], 0.f); a[j] = be2[lane]; }
    for (int i = 0; i < 64; i += 4) {
        float4 bb[8];
        #pragma unroll
        for (int j = 0; j < 8; ++j) bb[j] = *(const float4*)&st[w][j][i];
        #pragma unroll
        for (int ii = 0; ii < 4; ++ii) {
            float wv = We2T[(i + ii) * 64 + lane];
            #pragma unroll
            for (int j = 0; j < 8; ++j) a[j] += ((const float*)&bb[j])[ii] * wv;
        }
    }
    #pragma unroll
    for (int j = 0; j < 8; ++j)
        ew16[(size_t)(e0 + j) * 64 + lane] = (f16)fmaxf(a[j], 0.f);
}

// ---------------- message GEMM (MFMA f16) + scatter ----------------
__device__ __forceinline__ half8 splat8(f16 v)
{ half8 r = { v, v, v, v, v, v, v, v }; return r; }

__device__ __forceinline__ void mfma_block(
    const char* bb, int swzA, int swzB,
    half8 aA0, half8 aA1, half8 aB0, half8 aB1, f32x4 (&acc)[2][4])
{
    half8 b00 = *(const half8*)(bb + 0    + swzA);
    half8 b01 = *(const half8*)(bb + 0    + swzB);
    half8 b10 = *(const half8*)(bb + 2048 + swzA);
    half8 b11 = *(const half8*)(bb + 2048 + swzB);
    half8 b20 = *(const half8*)(bb + 4096 + swzA);
    half8 b21 = *(const half8*)(bb + 4096 + swzB);
    half8 b30 = *(const half8*)(bb + 6144 + swzA);
    half8 b31 = *(const half8*)(bb + 6144 + swzB);
    acc[0][0] = __builtin_amdgcn_mfma_f32_16x16x32_f16(aA0, b00, acc[0][0], 0, 0, 0);
    acc[0][0] = __builtin_amdgcn_mfma_f32_16x16x32_f16(aA1, b01, acc[0][0], 0, 0, 0);
    acc[0][1] = __builtin_amdgcn_mfma_f32_16x16x32_f16(aA0, b10, acc[0][1], 0, 0, 0);
    acc[0][1] = __builtin_amdgcn_mfma_f32_16x16x32_f16(aA1, b11, acc[0][1], 0, 0, 0);
    acc[0][2] = __builtin_amdgcn_mfma_f32_16x16x32_f16(aA0, b20, acc[0][2], 0, 0, 0);
    acc[0][2] = __builtin_amdgcn_mfma_f32_16x16x32_f16(aA1, b21, acc[0][2], 0, 0, 0);
    acc[0][3] = __builtin_amdgcn_mfma_f32_16x16x32_f16(aA0, b30, acc[0][3], 0, 0, 0);
    acc[0][3] = __builtin_amdgcn_mfma_f32_16x16x32_f16(aA1, b31, acc[0][3], 0, 0, 0);
    acc[1][0] = __builtin_amdgcn_mfma_f32_16x16x32_f16(aB0, b00, acc[1][0], 0, 0, 0);
    acc[1][0] = __builtin_amdgcn_mfma_f32_16x16x32_f16(aB1, b01, acc[1][0], 0, 0, 0);
    acc[1][1] = __builtin_amdgcn_mfma_f32_16x16x32_f16(aB0, b10, acc[1][1], 0, 0, 0);
    acc[1][1] = __builtin_amdgcn_mfma_f32_16x16x32_f16(aB1, b11, acc[1][1], 0, 0, 0);
    acc[1][2] = __builtin_amdgcn_mfma_f32_16x16x32_f16(aB0, b20, acc[1][2], 0, 0, 0);
    acc[1][2] = __builtin_amdgcn_mfma_f32_16x16x32_f16(aB1, b21, acc[1][2], 0, 0, 0);
    acc[1][3] = __builtin_amdgcn_mfma_f32_16x16x32_f16(aB0, b30, acc[1][3], 0, 0, 0);
    acc[1][3] = __builtin_amdgcn_mfma_f32_16x16x32_f16(aB1, b31, acc[1][3], 0, 0, 0);
}

// msg[E,64] = P[E,4160] @ [Wf16; be3T], P[e, i*64+k] = h16[src_e,i]*ew16[e,k].
// Round-6 structure (proven) + 2-slab windows: 4-slab B ring (32KB) built by
// reclaiming the ew-staging space after the K-invariant register hoist.
// Barriers 65 -> 34; LDS 51.7KB keeps 3 blocks/CU. Same XOR swizzle pair
// (write dsw / read swz) as round 6; ew staging gets its own XOR swizzle.
__global__ __launch_bounds__(256) void msg_mfma(
    const f16* __restrict__ h16, const f16* __restrict__ ew16,
    const f16* __restrict__ Wf16, const int* __restrict__ edge_index,
    float* __restrict__ aggr)
{
    __shared__ f16 sh_h[128][72];      // 18432 B
    __shared__ f16 sh_ring[4][4096];   // 32768 B: ew staging, then 4-slab B ring
    __shared__ int sh_dst[128];
    int t = threadIdx.x, lane = t & 63, wv = t >> 6;
    int e0 = blockIdx.x * 128;
    char* ringc = (char*)&sh_ring[0][0];

    // issue slabs 0,1 global loads first (hide under gather)
    const uint4* gW = (const uint4*)Wf16;            // 512 uint4 per 8KB slab
    uint4 r0 = gW[t], r1 = gW[256 + t], r2 = gW[512 + t], r3 = gW[768 + t];

    {   // gather 128 h-rows (padded) + 128 ew-rows (packed+swizzled into ring)
        int row = t >> 1, part = t & 1;
        int e = e0 + row;
        bool valid = e < NE;
        int ec = valid ? e : NE - 1;
        int src = edge_index[ec];
        const uint4* hp = (const uint4*)(h16 + (size_t)src * 64 + part * 32);
        const uint4* ep = (const uint4*)(ew16 + (size_t)ec * 64 + part * 32);
        uint4 z = make_uint4(0u, 0u, 0u, 0u);
        uint4 h0 = hp[0], h1 = hp[1], h2 = hp[2], h3 = hp[3];
        uint4 g0 = valid ? ep[0] : z;
        uint4 g1 = valid ? ep[1] : z;
        uint4 g2 = valid ? ep[2] : z;
        uint4 g3 = valid ? ep[3] : z;
        *(uint4*)&sh_h[row][part * 32]      = h0;
        *(uint4*)&sh_h[row][part * 32 + 8]  = h1;
        *(uint4*)&sh_h[row][part * 32 + 16] = h2;
        *(uint4*)&sh_h[row][part * 32 + 24] = h3;
        int rb = row * 128, key = (row & 7) << 4;    // ew: stride 128B + XOR swz
        *(uint4*)(ringc + rb + ((part * 64 +  0) ^ key)) = g0;
        *(uint4*)(ringc + rb + ((part * 64 + 16) ^ key)) = g1;
        *(uint4*)(ringc + rb + ((part * 64 + 32) ^ key)) = g2;
        *(uint4*)(ringc + rb + ((part * 64 + 48) ^ key)) = g3;
        if (lane < 32) {                             // per-wave dst stage
            int e2 = e0 + wv * 32 + lane;
            sh_dst[wv * 32 + lane] = (e2 < NE) ? edge_index[NE + e2] : -1;
        }
    }

    int r16 = lane & 15, kq = lane >> 4;
    int row0 = wv * 32 + r16, row1 = row0 + 16;

    // in-wave hoist of K-invariant ew fragments (reads wave's own rows)
    int k0 = (row0 & 7) << 4, k1 = (row1 & 7) << 4;
    half8 evA0 = *(const half8*)(ringc + row0 * 128 + ((kq * 16) ^ k0));
    half8 evA1 = *(const half8*)(ringc + row0 * 128 + ((64 + kq * 16) ^ k0));
    half8 evB0 = *(const half8*)(ringc + row1 * 128 + ((kq * 16) ^ k1));
    half8 evB1 = *(const half8*)(ringc + row1 * 128 + ((64 + kq * 16) ^ k1));

    __syncthreads();                  // barrier1: hoists done, ring free, dst visible

    int d0 = t * 16, d1 = 4096 + t * 16;
    int dsw0 = d0 ^ (((d0 >> 7) & 7) << 4);
    int dsw1 = d1 ^ (((d1 >> 7) & 7) << 4);

    // write pair0 (slabs 0,1); issue slabs 2,3
    *(uint4*)(ringc + dsw0) = r0;
    *(uint4*)(ringc + dsw1) = r1;
    *(uint4*)(ringc + 8192 + dsw0) = r2;
    *(uint4*)(ringc + 8192 + dsw1) = r3;
    r0 = gW[2 * 512 + t]; r1 = gW[2 * 512 + 256 + t];
    r2 = gW[3 * 512 + t]; r3 = gW[3 * 512 + 256 + t];
    __syncthreads();                  // barrier2: pair0 ready

    f32x4 acc[2][4];
    #pragma unroll
    for (int m = 0; m < 2; ++m)
        #pragma unroll
        for (int n = 0; n < 4; ++n) acc[m][n] = (f32x4){0, 0, 0, 0};

    int swzA = (kq << 4) ^ ((r16 & 7) << 4);
    int swzB = ((kq << 4) | 64) ^ ((r16 & 7) << 4);

    for (int i8 = 0; i8 < 8; ++i8) {                 // 8 K-slabs = 4 windows
        half8 hA = *(const half8*)&sh_h[row0][i8 * 8];
        half8 hB = *(const half8*)&sh_h[row1][i8 * 8];
        #pragma unroll
        for (int w2 = 0; w2 < 4; ++w2) {             // window: 2 slabs, 32 MFMA
            const char* pairR = ringc + (w2 & 1) * 16384 + r16 * 128;
            #pragma unroll
            for (int s = 0; s < 2; ++s) {
                f16 hsA = hA[w2 * 2 + s];            // static index
                f16 hsB = hB[w2 * 2 + s];
                mfma_block(pairR + s * 8192, swzA, swzB,
                           evA0 * splat8(hsA), evA1 * splat8(hsA),
                           evB0 * splat8(hsB), evB1 * splat8(hsB), acc);
            }
            // stage next pair (regs hold slabs 2jw+2, 2jw+3), issue jw+2's pair
            char* wb = ringc + ((w2 + 1) & 1) * 16384;
            *(uint4*)(wb + dsw0) = r0;
            *(uint4*)(wb + dsw1) = r1;
            *(uint4*)(wb + 8192 + dsw0) = r2;
            *(uint4*)(wb + 8192 + dsw1) = r3;
            int jw = i8 * 4 + w2;
            int sA = jw * 2 + 4; if (sA > 64) sA = 64;   // slab 64 = bias slab
            int sB = jw * 2 + 5; if (sB > 64) sB = 64;
            r0 = gW[(size_t)sA * 512 + t]; r1 = gW[(size_t)sA * 512 + 256 + t];
            r2 = gW[(size_t)sB * 512 + t]; r3 = gW[(size_t)sB * 512 + 256 + t];
            __syncthreads();
        }
    }

    {   // bias slab (64) sits in pair0 half0: A = h16 rows, B = be3T
        const char* bb = ringc + r16 * 128;
        half8 aA0 = *(const half8*)&sh_h[row0][kq * 8];
        half8 aA1 = *(const half8*)&sh_h[row0][32 + kq * 8];
        half8 aB0 = *(const half8*)&sh_h[row1][kq * 8];
        half8 aB1 = *(const half8*)&sh_h[row1][32 + kq * 8];
        mfma_block(bb, swzA, swzB, aA0, aA1, aB0, aB1, acc);
    }

    // scatter: C/D layout col=lane&15, row=(lane>>4)*4+reg  [m89-verified]
    #pragma unroll
    for (int m = 0; m < 2; ++m) {
        #pragma unroll
        for (int reg = 0; reg < 4; ++reg) {
            int e_l = wv * 32 + m * 16 + kq * 4 + reg;
            int d = sh_dst[e_l];
            if (d >= 0) {
                float* ap = aggr + (size_t)d * 64 + r16;
                atomicAdd(ap,      acc[m][0][reg]);
                atomicAdd(ap + 16, acc[m][1][reg]);
                atomicAdd(ap + 32, acc[m][2][reg]);
                atomicAdd(ap + 48, acc[m][3][reg]);
            }
        }
    }
}

// ---------------- fused root-term + GRU step: 8 nodes per wave ----------------
// hid buffer eliminated: hidden==hbuf after layer 0 (first==0 -> dv=hv),
// hidden==0 at layer 0 (first==1 -> skip hh matvec, gh=bhh). Also zeroes
// aggr in-place for the next layer's scatter (replaces hipMemsetAsync).
__global__ __launch_bounds__(256) void gru_kernel(
    float* __restrict__ aggr, float* __restrict__ hbuf, f16* __restrict__ h16,
    const float* __restrict__ root, const float* __restrict__ cbias,
    const float* __restrict__ T, const float* __restrict__ bih,
    const float* __restrict__ bhh, float* __restrict__ out2, int first)
{
    __shared__ float sm_h[4][8][64];
    __shared__ float sm_m[4][8][64];
    const float* WihT = T + 15360;    // [64][192]
    const float* WhhT = T + 27648;    // [64][192]
    int w = threadIdx.x >> 6, lane = threadIdx.x & 63;
    int n0 = blockIdx.x * 32 + w * 8;
    if (n0 >= NN) return;             // NN%8==0

    float hv[8], m[8];
    #pragma unroll
    for (int j = 0; j < 8; ++j) {
        size_t idx = (size_t)(n0 + j) * 64 + lane;
        hv[j] = hbuf[idx];
        sm_h[w][j][lane] = hv[j];
        m[j] = aggr[idx] + cbias[lane];
        aggr[idx] = 0.f;              // ready for next layer's atomics
    }
    for (int i = 0; i < 64; i += 4) { // m += h @ root
        float4 bb[8];
        #pragma unroll
        for (int j = 0; j < 8; ++j) bb[j] = *(const float4*)&sm_h[w][j][i];
        #pragma unroll
        for (int ii = 0; ii < 4; ++ii) {
            float rv = root[(i + ii) * 64 + lane];
            #pragma unroll
            for (int j = 0; j < 8; ++j) m[j] += ((const float*)&bb[j])[ii] * rv;
        }
    }
    #pragma unroll
    for (int j = 0; j < 8; ++j) sm_m[w][j][lane] = m[j];

    float gr[8], gz[8], gn[8], hr[8], hz[8], hn[8];
    #pragma unroll
    for (int j = 0; j < 8; ++j) {
        gr[j] = bih[lane]; gz[j] = bih[64 + lane]; gn[j] = bih[128 + lane];
        hr[j] = bhh[lane]; hz[j] = bhh[64 + lane]; hn[j] = bhh[128 + lane];
    }
    for (int i = 0; i < 64; i += 2) {
        float2 bm[8], bh[8];
        #pragma unroll
        for (int j = 0; j < 8; ++j) {
            bm[j] = *(const float2*)&sm_m[w][j][i];
            bh[j] = *(const float2*)&sm_h[w][j][i];
        }
        #pragma unroll
        for (int ii = 0; ii < 2; ++ii) {
            float wr = WihT[(i + ii) * 192 + lane];
            float wz = WihT[(i + ii) * 192 + 64 + lane];
            float wn = WihT[(i + ii) * 192 + 128 + lane];
            #pragma unroll
            for (int j = 0; j < 8; ++j) {
                float mv = ((const float*)&bm[j])[ii];
                gr[j] += mv * wr; gz[j] += mv * wz; gn[j] += mv * wn;
            }
            if (!first) {
                float vr = WhhT[(i + ii) * 192 + lane];
                float vz = WhhT[(i + ii) * 192 + 64 + lane];
                float vn = WhhT[(i + ii) * 192 + 128 + lane];
                #pragma unroll
                for (int j = 0; j < 8; ++j) {
                    float dv = ((const float*)&bh[j])[ii];
                    hr[j] += dv * vr; hz[j] += dv * vz; hn[j] += dv * vn;
                }
            }
        }
    }

    #pragma unroll
    for (int j = 0; j < 8; ++j) {
        float r  = 1.f / (1.f + expf(-(gr[j] + hr[j])));
        float z  = 1.f / (1.f + expf(-(gz[j] + hz[j])));
        float nv = tanhf(gn[j] + r * hn[j]);
        float dvv = first ? 0.f : hv[j];
        float outv = (1.f - z) * nv + z * dvv;
        size_t idx = (size_t)(n0 + j) * 64 + lane;
        hbuf[idx] = outv;
        h16[idx]  = (f16)outv;
        if (out2) out2[idx] = outv;
    }
}

extern "C" void kernel_launch(void* const* d_in, const int* in_sizes, int n_in,
                              void* d_out, int out_size, void* d_ws, size_t ws_size,
                              hipStream_t stream)
{
    const float* x   = (const float*)d_in[0];
    const float* ea  = (const float*)d_in[1];
    const float* Wn1 = (const float*)d_in[2];  const float* bn1 = (const float*)d_in[3];
    const float* Wn2 = (const float*)d_in[4];  const float* bn2 = (const float*)d_in[5];
    const float* Wn3 = (const float*)d_in[6];  const float* bn3 = (const float*)d_in[7];
    const float* We1 = (const float*)d_in[8];  const float* be1 = (const float*)d_in[9];
    const float* We2 = (const float*)d_in[10]; const float* be2 = (const float*)d_in[11];
    const float* We3 = (const float*)d_in[12]; const float* be3 = (const float*)d_in[13];
    const float* roots = (const float*)d_in[14];
    const float* cb    = (const float*)d_in[15];
    const float* Wih = (const float*)d_in[16]; const float* Whh = (const float*)d_in[17];
    const float* bih = (const float*)d_in[18]; const float* bhh = (const float*)d_in[19];
    const int*   ei  = (const int*)d_in[20];

    // ws layout: fp32 region then fp16 region (16B-aligned), ~29.5 MB total
    float* ws   = (float*)d_ws;
    float* hbuf = ws;                               // N*64
    float* aggr = hbuf + (size_t)NN * 64;           // N*64
    float* Tbuf = aggr + (size_t)NN * 64;           // 39936 (pad to 40960)
    f16*   h16  = (f16*)(ws + 2 * (size_t)NN * 64 + 40960);   // N*64
    f16*   ew16 = h16  + (size_t)NN * 64;                     // E*64
    f16*   Wf16 = ew16 + (size_t)NE * 64;                     // 65*4096

    prep_all<<<(306176) / 256, 256, 0, stream>>>(Wn1, Wn2, Wn3, We1, We2,
                                                 Wih, Whh, We3, be3, Tbuf, Wf16);
    node_mlp<<<(NN + 31) / 32, 256, 0, stream>>>(x, Tbuf, bn1, bn2, bn3,
                                                 hbuf, h16, aggr);
    edge_mlp<<<NE / 32, 256, 0, stream>>>(ea, Tbuf, be1, be2, ew16);

    for (int l = 0; l < 3; ++l) {
        msg_mfma<<<(NE + 127) / 128, 256, 0, stream>>>(h16, ew16, Wf16, ei, aggr);
        gru_kernel<<<(NN + 31) / 32, 256, 0, stream>>>(aggr, hbuf, h16,
            roots + (size_t)l * 4096, cb + (size_t)l * 64,
            Tbuf, bih, bhh, (l == 2) ? (float*)d_out : nullptr, (l == 0) ? 1 : 0);
    }
}